// Round 5
// baseline (7353.738 us; speedup 1.0000x reference)
//
#include <hip/hip_runtime.h>
#include <math.h>

#define MTOK 16384
#define NEXP 256
#define KDIM 7168

#define CAPR 1024
#define KSPLIT 8
#define KCH (KDIM / KSPLIT)   // 896
#define TAU 2e-5f

#define NKC (KDIM / 32)       // 224 K-chunks of 32
#define WSTRIDE (NKC * 64)    // 14336 f16 per Wcomb row (= 28672 B)

typedef _Float16 f16;
typedef __attribute__((ext_vector_type(8))) f16 f16x8;
typedef __attribute__((ext_vector_type(4))) float f32x4;

__device__ __forceinline__ void cvt_hilo(const float4 a, const float4 b, f16x8* h, f16x8* l) {
    float xs[8] = {a.x, a.y, a.z, a.w, b.x, b.y, b.z, b.w};
#pragma unroll
    for (int e = 0; e < 8; ++e) {
        f16 hh = (f16)xs[e];
        (*h)[e] = hh;
        (*l)[e] = (f16)((xs[e] - (float)hh) * 2048.f);
    }
}

// ============ K0: W -> Wcomb (hi|lo f16, per-row-swizzled, per 32-k chunk) ============
// Wcomb[row][kc][g'] (g'=0..7, 8 f16 each): g = g'^(row&7); g<4 -> hi of k [g*8..g*8+7]
//                                           else lo of k [(g-4)*8 .. +7]
__global__ void wconv_k(const float* __restrict__ W, f16* __restrict__ Wcomb) {
    const int row = blockIdx.x;
    const int kc  = threadIdx.x;      // 0..223
    const float* src = W + (size_t)row * KDIM + kc * 32;
    float x[32];
#pragma unroll
    for (int i = 0; i < 8; ++i) {
        float4 v = *(const float4*)(src + i * 4);
        x[i * 4 + 0] = v.x; x[i * 4 + 1] = v.y; x[i * 4 + 2] = v.z; x[i * 4 + 3] = v.w;
    }
    const int key = row & 7;
    f16* dst = Wcomb + (size_t)row * WSTRIDE + kc * 64;
#pragma unroll
    for (int gp = 0; gp < 8; ++gp) {
        const int g = gp ^ key;
        f16x8 o;
        if (g < 4) {
#pragma unroll
            for (int e = 0; e < 8; ++e) o[e] = (f16)x[g * 8 + e];
        } else {
#pragma unroll
            for (int e = 0; e < 8; ++e) {
                float xv = x[(g - 4) * 8 + e];
                f16 hh = (f16)xv;
                o[e] = (f16)((xv - (float)hh) * 2048.f);
            }
        }
        *(f16x8*)(dst + gp * 8) = o;
    }
}

// ============ K1: fp16x2-split MFMA GEMM + sigmoid ============
// BM=64, BN=128, BK=32; 2 waves, wave-tile 64x64; swizzled LDS (key=row&7)
__launch_bounds__(128, 2)
__global__ void gemm_v5_k(const float* __restrict__ X,
                          const f16* __restrict__ Wcomb,
                          float* __restrict__ S) {
    __shared__ f16 Asw[64][64];    // [row][hi g0..3 | lo g4..7], swizzled
    __shared__ f16 Bsw[128][64];

    const int tid  = threadIdx.x;
    const int lane = tid & 63;
    const int wid  = tid >> 6;          // 0..1 -> N half
    const int m0 = blockIdx.y * 64;
    const int n0 = blockIdx.x * 128;

    // A staging map: 64 rows x 32 k; thread covers row tid>>1, k-half (tid&1)*16
    const int arow = tid >> 1;
    const int akh  = tid & 1;
    const float* xg = X + (size_t)(m0 + arow) * KDIM + akh * 16;
    const int akey  = arow & 7;
    const int gbase = akh * 2;

    // B staging map: thread owns LDS row tid (0..127)
    const f16* wsrc = Wcomb + (size_t)(n0 + tid) * WSTRIDE;
    const int rot = tid & 7;

    const int fr = lane & 15;
    const int fq = lane >> 4;
    const int rkey = fr & 7;

    f32x4 accA[4][4];
    f32x4 accB[4][4];
#pragma unroll
    for (int i = 0; i < 4; ++i)
#pragma unroll
        for (int j = 0; j < 4; ++j) { accA[i][j] = (f32x4)0.f; accB[i][j] = (f32x4)0.f; }

    for (int kc = 0; kc < NKC; ++kc) {
        const int k0 = kc * 32;
        // loads (before barrier; hit memory while previous compute finishes)
        float4 a0 = *(const float4*)(xg + k0 + 0);
        float4 a1 = *(const float4*)(xg + k0 + 4);
        float4 a2 = *(const float4*)(xg + k0 + 8);
        float4 a3 = *(const float4*)(xg + k0 + 12);
        f16x8 bv[8];
#pragma unroll
        for (int s = 0; s < 8; ++s) bv[s] = *(const f16x8*)(wsrc + k0 * 2 + s * 8);

        __syncthreads();   // previous iteration's fragment reads complete

        // A: cvt + swizzled writes (b128)
        {
            f16x8 h0, l0, h1, l1;
            cvt_hilo(a0, a1, &h0, &l0);
            cvt_hilo(a2, a3, &h1, &l1);
            *(f16x8*)&Asw[arow][((gbase + 0) ^ akey) * 8] = h0;
            *(f16x8*)&Asw[arow][((gbase + 1) ^ akey) * 8] = h1;
            *(f16x8*)&Asw[arow][((gbase + 4) ^ akey) * 8] = l0;
            *(f16x8*)&Asw[arow][((gbase + 5) ^ akey) * 8] = l1;
        }
        // B: rotated stores (bank-spread); content already hi/lo+swizzled
#pragma unroll
        for (int j = 0; j < 8; ++j) {
            const int s = (j + rot) & 7;
            *(f16x8*)&Bsw[tid][s * 8] = bv[s];
        }

        __syncthreads();

        // fragments
        f16x8 ah[4], al[4];
#pragma unroll
        for (int mi = 0; mi < 4; ++mi) {
            const int r = mi * 16 + fr;
            ah[mi] = *(const f16x8*)&Asw[r][((fq + 0) ^ rkey) * 8];
            al[mi] = *(const f16x8*)&Asw[r][((fq + 4) ^ rkey) * 8];
        }
#pragma unroll
        for (int ni = 0; ni < 4; ++ni) {
            const int r = wid * 64 + ni * 16 + fr;
            f16x8 bh = *(const f16x8*)&Bsw[r][((fq + 0) ^ rkey) * 8];
            f16x8 bl = *(const f16x8*)&Bsw[r][((fq + 4) ^ rkey) * 8];
#pragma unroll
            for (int mi = 0; mi < 4; ++mi) {
                accA[mi][ni] = __builtin_amdgcn_mfma_f32_16x16x32_f16(ah[mi], bh, accA[mi][ni], 0, 0, 0);
                accB[mi][ni] = __builtin_amdgcn_mfma_f32_16x16x32_f16(ah[mi], bl, accB[mi][ni], 0, 0, 0);
                accB[mi][ni] = __builtin_amdgcn_mfma_f32_16x16x32_f16(al[mi], bh, accB[mi][ni], 0, 0, 0);
            }
        }
    }

    // epilogue: combine, sigmoid, store (C layout: row=(lane>>4)*4+r, col=lane&15)
#pragma unroll
    for (int mi = 0; mi < 4; ++mi)
#pragma unroll
        for (int ni = 0; ni < 4; ++ni) {
            const int e = n0 + wid * 64 + ni * 16 + fr;
#pragma unroll
            for (int r = 0; r < 4; ++r) {
                const int m = m0 + mi * 16 + fq * 4 + r;
                float logit = accA[mi][ni][r] + accB[mi][ni][r] * (1.f / 2048.f);
                S[(size_t)m * NEXP + e] = 1.f / (1.f + expf(-logit));
            }
        }
}

// ================= K2: f32 routing + margin flagging =================
__launch_bounds__(256)
__global__ void route_flag_k(const float* __restrict__ S,
                             const float* __restrict__ bias,
                             float* __restrict__ out,
                             int* __restrict__ list,
                             int* __restrict__ count) {
    __shared__ float sraw[4][256];
    const int wv   = threadIdx.x >> 6;
    const int lane = threadIdx.x & 63;
    const int token = blockIdx.x * 4 + wv;
    const float NINF = -__builtin_inff();
    const float PINF =  __builtin_inff();

    const float* row = S + (size_t)token * NEXP;
    float4 v = *(const float4*)(row + lane * 4);
    *(float4*)&sraw[wv][lane * 4] = v;

    const int e0 = lane * 4;
    float4 bi4 = *(const float4*)(bias + e0);
    float b0 = v.x + bi4.x;
    float b1 = v.y + bi4.y;
    float b2 = v.z + bi4.z;
    float b3 = v.w + bi4.w;

    bool flag = false;

    float m1 = b0, m2 = NINF;
    if (b1 > m1) { m2 = m1; m1 = b1; } else if (b1 > m2) m2 = b1;
    if (b2 > m1) { m2 = m1; m1 = b2; } else if (b2 > m2) m2 = b2;
    if (b3 > m1) { m2 = m1; m1 = b3; } else if (b3 > m2) m2 = b3;
#pragma unroll
    for (int w = 1; w <= 4; w <<= 1) {
        float o1 = __shfl_xor(m1, w);
        float o2 = __shfl_xor(m2, w);
        float nm1 = fmaxf(m1, o1);
        float nm2 = fmaxf(fminf(m1, o1), fmaxf(m2, o2));
        m1 = nm1; m2 = nm2;
    }
    const float gs = m1 + m2;
    const int g = lane >> 3;

    int rank = 0;
#pragma unroll
    for (int j = 0; j < 8; ++j) {
        float gj = __shfl(gs, j * 8);
        rank += (gj > gs) || (gj == gs && j < g);
    }
    const bool sel = rank < 4;

    {
        float a = sel ? gs : PINF;
        float b = sel ? NINF : gs;
#pragma unroll
        for (int w = 1; w < 64; w <<= 1) {
            a = fminf(a, __shfl_xor(a, w));
            b = fmaxf(b, __shfl_xor(b, w));
        }
        flag |= (a - b) < 2.f * TAU;
    }

    if (!sel) { b0 = NINF; b1 = NINF; b2 = NINF; b3 = NINF; }

    int myidx = 0;
    float prev = 0.f;
#pragma unroll
    for (int it = 0; it < 9; ++it) {
        float bv = b0; int bi = e0;
        if (b1 > bv) { bv = b1; bi = e0 + 1; }
        if (b2 > bv) { bv = b2; bi = e0 + 2; }
        if (b3 > bv) { bv = b3; bi = e0 + 3; }
#pragma unroll
        for (int w = 1; w < 64; w <<= 1) {
            float ov = __shfl_xor(bv, w);
            int   oi = __shfl_xor(bi, w);
            if (ov > bv || (ov == bv && oi < bi)) { bv = ov; bi = oi; }
        }
        if (it > 0) flag |= (prev - bv) < TAU;
        prev = bv;
        if (it < 8) {
            if (lane == it) myidx = bi;
            if ((bi >> 2) == lane) {
                switch (bi & 3) {
                    case 0: b0 = NINF; break;
                    case 1: b1 = NINF; break;
                    case 2: b2 = NINF; break;
                    case 3: b3 = NINF; break;
                }
            }
        }
    }

    const bool anyflag = __any((int)flag);

    __syncthreads();

    float wval = (lane < 8) ? sraw[wv][myidx] : 0.f;
    float s = wval;
    s += __shfl_xor(s, 1);
    s += __shfl_xor(s, 2);
    s += __shfl_xor(s, 4);
    if (lane < 8) {
        float wout = wval / (s + 1e-20f) * 2.5f;
        out[(size_t)token * 8 + lane] = wout;
        out[(size_t)MTOK * 8 + (size_t)token * 8 + lane] = (float)myidx;
    }

    if (anyflag && lane == 0) {
        int f = atomicAdd(count, 1);
        if (f < CAPR) list[f] = token;
    }
}

// ================= K3: K-split f64 partial GEMM over flagged rows =================
__launch_bounds__(256)
__global__ void rescore_k(const float* __restrict__ X,
                          const float* __restrict__ W,
                          const int* __restrict__ list,
                          const int* __restrict__ count,
                          double* __restrict__ Ldp) {
    const int cnt = min(*count, CAPR);
    const int m0 = blockIdx.x * 64;
    if (m0 >= cnt) return;
    const int n0 = blockIdx.y * 64;
    const int ks = blockIdx.z;
    const int kbase = ks * KCH;

    __shared__ float As[16][66];
    __shared__ float Bs[16][66];
    const int tid = threadIdx.x;
    const int row = tid >> 2;
    const int c   = tid & 3;
    const int tm  = tid >> 4;
    const int tn  = tid & 15;

    const int gi = list[min(m0 + row, cnt - 1)];
    const float* xg = X + (size_t)gi * KDIM + c * 4;
    const float* wg = W + (size_t)(n0 + row) * KDIM + c * 4;

    double acc[4][4];
#pragma unroll
    for (int i = 0; i < 4; ++i)
#pragma unroll
        for (int j = 0; j < 4; ++j) acc[i][j] = 0.0;

    for (int k0 = kbase; k0 < kbase + KCH; k0 += 16) {
        float4 a = *(const float4*)(xg + k0);
        float4 b = *(const float4*)(wg + k0);
        __syncthreads();
        As[c * 4 + 0][row] = a.x; As[c * 4 + 1][row] = a.y;
        As[c * 4 + 2][row] = a.z; As[c * 4 + 3][row] = a.w;
        Bs[c * 4 + 0][row] = b.x; Bs[c * 4 + 1][row] = b.y;
        Bs[c * 4 + 2][row] = b.z; Bs[c * 4 + 3][row] = b.w;
        __syncthreads();
#pragma unroll
        for (int k = 0; k < 16; ++k) {
            double ad[4], bd[4];
#pragma unroll
            for (int i = 0; i < 4; ++i) ad[i] = (double)As[k][tm * 4 + i];
#pragma unroll
            for (int j = 0; j < 4; ++j) bd[j] = (double)Bs[k][tn * 4 + j];
#pragma unroll
            for (int i = 0; i < 4; ++i)
#pragma unroll
                for (int j = 0; j < 4; ++j)
                    acc[i][j] = fma(ad[i], bd[j], acc[i][j]);
        }
    }

#pragma unroll
    for (int i = 0; i < 4; ++i) {
        const int r = m0 + tm * 4 + i;
        if (r < cnt) {
#pragma unroll
            for (int j = 0; j < 4; ++j)
                Ldp[((size_t)ks * CAPR + r) * NEXP + n0 + tn * 4 + j] = acc[i][j];
        }
    }
}

// ================= K4: exact f64 routing for flagged tokens =================
__launch_bounds__(64)
__global__ void route_exact_k(const double* __restrict__ Ldp,
                              const float* __restrict__ bias,
                              const int* __restrict__ list,
                              const int* __restrict__ count,
                              float* __restrict__ out) {
    const int cnt = min(*count, CAPR);
    const int f = blockIdx.x;
    if (f >= cnt) return;
    const int lane = threadIdx.x;
    const int token = list[f];
    const double NINF = -__builtin_inf();

    const int e0 = lane * 4;
    double l0 = 0.0, l1 = 0.0, l2 = 0.0, l3 = 0.0;
#pragma unroll
    for (int s = 0; s < KSPLIT; ++s) {
        double4 p = *(const double4*)(Ldp + ((size_t)s * CAPR + f) * NEXP + e0);
        l0 += p.x; l1 += p.y; l2 += p.z; l3 += p.w;
    }

    double s0 = 1.0 / (1.0 + exp(-l0));
    double s1 = 1.0 / (1.0 + exp(-l1));
    double s2 = 1.0 / (1.0 + exp(-l2));
    double s3 = 1.0 / (1.0 + exp(-l3));

    float4 bi4 = *(const float4*)(bias + e0);
    double b0 = s0 + (double)bi4.x;
    double b1 = s1 + (double)bi4.y;
    double b2 = s2 + (double)bi4.z;
    double b3 = s3 + (double)bi4.w;

    double m1 = b0, m2 = NINF;
    if (b1 > m1) { m2 = m1; m1 = b1; } else if (b1 > m2) m2 = b1;
    if (b2 > m1) { m2 = m1; m1 = b2; } else if (b2 > m2) m2 = b2;
    if (b3 > m1) { m2 = m1; m1 = b3; } else if (b3 > m2) m2 = b3;
#pragma unroll
    for (int w = 1; w <= 4; w <<= 1) {
        double o1 = __shfl_xor(m1, w);
        double o2 = __shfl_xor(m2, w);
        double nm1 = fmax(m1, o1);
        double nm2 = fmax(fmin(m1, o1), fmax(m2, o2));
        m1 = nm1; m2 = nm2;
    }
    const double gs = m1 + m2;
    const int g = lane >> 3;

    int rank = 0;
#pragma unroll
    for (int j = 0; j < 8; ++j) {
        double gj = __shfl(gs, j * 8);
        rank += (gj > gs) || (gj == gs && j < g);
    }
    if (rank >= 4) { b0 = NINF; b1 = NINF; b2 = NINF; b3 = NINF; }

    int myidx = 0;
#pragma unroll
    for (int it = 0; it < 8; ++it) {
        double bv = b0; int bi = e0;
        if (b1 > bv) { bv = b1; bi = e0 + 1; }
        if (b2 > bv) { bv = b2; bi = e0 + 2; }
        if (b3 > bv) { bv = b3; bi = e0 + 3; }
#pragma unroll
        for (int w = 1; w < 64; w <<= 1) {
            double ov = __shfl_xor(bv, w);
            int    oi = __shfl_xor(bi, w);
            if (ov > bv || (ov == bv && oi < bi)) { bv = ov; bi = oi; }
        }
        if (lane == it) myidx = bi;
        if ((bi >> 2) == lane) {
            switch (bi & 3) {
                case 0: b0 = NINF; break;
                case 1: b1 = NINF; break;
                case 2: b2 = NINF; break;
                case 3: b3 = NINF; break;
            }
        }
    }

    double g0 = __shfl(s0, myidx >> 2);
    double g1 = __shfl(s1, myidx >> 2);
    double g2 = __shfl(s2, myidx >> 2);
    double g3 = __shfl(s3, myidx >> 2);
    const int ss = myidx & 3;
    double wval = (lane < 8) ? (ss == 0 ? g0 : ss == 1 ? g1 : ss == 2 ? g2 : g3) : 0.0;
    double s = wval;
    s += __shfl_xor(s, 1);
    s += __shfl_xor(s, 2);
    s += __shfl_xor(s, 4);
    if (lane < 8) {
        float wout = (float)(wval / (s + 1e-20) * 2.5);
        out[(size_t)token * 8 + lane] = wout;
        out[(size_t)MTOK * 8 + (size_t)token * 8 + lane] = (float)myidx;
    }
}

__global__ void init_k(int* count) { *count = 0; }

extern "C" void kernel_launch(void* const* d_in, const int* in_sizes, int n_in,
                              void* d_out, int out_size, void* d_ws, size_t ws_size,
                              hipStream_t stream) {
    const float* X    = (const float*)d_in[0];
    const float* W    = (const float*)d_in[1];
    const float* bias = (const float*)d_in[2];
    float* out = (float*)d_out;

    // ws: [0,16.8MB) Lf f32 scores, later aliased by Ldp f64 partials (rescore
    //     runs after route_flag, when Lf is dead).  Then list, cnt, Wcomb.
    float*  Lf    = (float*)d_ws;
    double* Ldp   = (double*)d_ws;                        // 8*1024*256*8 = 16,777,216 B
    int*    list  = (int*)((char*)d_ws + 16777216);
    int*    cnt   = (int*)((char*)d_ws + 16777216 + CAPR * 4);
    f16*    Wcomb = (f16*)((char*)d_ws + 16777216 + 65536); // 256*14336*2 = 7.34 MB

    init_k<<<1, 1, 0, stream>>>(cnt);
    wconv_k<<<NEXP, NKC, 0, stream>>>(W, Wcomb);

    dim3 g1(NEXP / 128, MTOK / 64);                       // (2, 256)
    gemm_v5_k<<<g1, 128, 0, stream>>>(X, Wcomb, Lf);

    route_flag_k<<<MTOK / 4, 256, 0, stream>>>(Lf, bias, out, list, cnt);

    dim3 g3(CAPR / 64, NEXP / 64, KSPLIT);
    rescore_k<<<g3, 256, 0, stream>>>(X, W, list, cnt, Ldp);

    route_exact_k<<<CAPR, 64, 0, stream>>>(Ldp, bias, list, cnt, out);
}

// Round 6
// 1612.481 us; speedup vs baseline: 4.5605x; 4.5605x over previous
//
#include <hip/hip_runtime.h>
#include <math.h>

#define MTOK 16384
#define NEXP 256
#define KDIM 7168

#define CAPR 1024
#define KSPLIT 8
#define KCH (KDIM / KSPLIT)   // 896
#define TAU 2e-5f

#define NKC (KDIM / 32)       // 224 K-chunks of 32
#define WSTRIDE (NKC * 64)    // 14336 f16 per Wcomb row (28672 B)

typedef _Float16 f16;
typedef __attribute__((ext_vector_type(8))) f16 f16x8;
typedef __attribute__((ext_vector_type(4))) float f32x4;

__device__ __forceinline__ void cvt_hilo(const float4 a, const float4 b, f16x8* h, f16x8* l) {
    float xs[8] = {a.x, a.y, a.z, a.w, b.x, b.y, b.z, b.w};
#pragma unroll
    for (int e = 0; e < 8; ++e) {
        f16 hh = (f16)xs[e];
        (*h)[e] = hh;
        (*l)[e] = (f16)((xs[e] - (float)hh) * 2048.f);
    }
}

// ============ K0: W -> Wcomb, LINEAR granules (hi g0..3 | lo g4..7) ============
__global__ void wconv_k(const float* __restrict__ W, f16* __restrict__ Wcomb) {
    const int row = blockIdx.x;
    const int kc  = threadIdx.x;      // 0..223
    const float* src = W + (size_t)row * KDIM + kc * 32;
    float x[32];
#pragma unroll
    for (int i = 0; i < 8; ++i) {
        float4 v = *(const float4*)(src + i * 4);
        x[i * 4 + 0] = v.x; x[i * 4 + 1] = v.y; x[i * 4 + 2] = v.z; x[i * 4 + 3] = v.w;
    }
    f16* dst = Wcomb + (size_t)row * WSTRIDE + kc * 64;
#pragma unroll
    for (int g = 0; g < 8; ++g) {
        f16x8 o;
        if (g < 4) {
#pragma unroll
            for (int e = 0; e < 8; ++e) o[e] = (f16)x[g * 8 + e];
        } else {
#pragma unroll
            for (int e = 0; e < 8; ++e) {
                float xv = x[(g - 4) * 8 + e];
                f16 hh = (f16)xv;
                o[e] = (f16)((xv - (float)hh) * 2048.f);
            }
        }
        *(f16x8*)(dst + g * 8) = o;
    }
}

// ============ K1: fp16x2-split MFMA GEMM + sigmoid (dbuf LDS, XOR swizzle) ============
// BM=64, BN=128, BK=32; 2 waves, wave-tile 64x64.
// LDS slot map: slot (g ^ (row&7)) holds granule g of row (g<4: hi k[g*8..+8); g>=4: lo).
__launch_bounds__(128, 2)
__global__ void gemm_v6_k(const float* __restrict__ X,
                          const f16* __restrict__ Wcomb,
                          float* __restrict__ S) {
    __shared__ f16 Asw[2][64][64];     // 16 KB
    __shared__ f16 Bsw[2][128][64];    // 32 KB

    const int tid  = threadIdx.x;
    const int lane = tid & 63;
    const int wid  = tid >> 6;          // 0..1 -> N half
    const int m0 = blockIdx.y * 64;
    const int n0 = blockIdx.x * 128;

    // A staging: thread covers row tid>>1 (0..63), k-half (tid&1)*16
    const int arow  = tid >> 1;
    const int akh   = tid & 1;
    const int akey  = arow & 7;
    const int gbase = akh * 2;
    const float* xg = X + (size_t)(m0 + arow) * KDIM + akh * 16;

    // B staging: thread owns LDS row tid (0..127)
    const f16* wsrc = Wcomb + (size_t)(n0 + tid) * WSTRIDE;
    const int brot = tid & 7;

    const int fr = lane & 15;
    const int fq = lane >> 4;
    const int rkey = fr & 7;

    f32x4 accA[4][4];
    f32x4 accB[4][4];
#pragma unroll
    for (int i = 0; i < 4; ++i)
#pragma unroll
        for (int j = 0; j < 4; ++j) { accA[i][j] = (f32x4)0.f; accB[i][j] = (f32x4)0.f; }

    // staging registers (all compile-time indexed)
    float4 a0, a1, a2, a3;
    f16x8 bv[8];

#define LOAD_TILE(K0_) do {                                                 \
        a0 = *(const float4*)(xg + (K0_) + 0);                              \
        a1 = *(const float4*)(xg + (K0_) + 4);                              \
        a2 = *(const float4*)(xg + (K0_) + 8);                              \
        a3 = *(const float4*)(xg + (K0_) + 12);                             \
        _Pragma("unroll")                                                   \
        for (int j_ = 0; j_ < 8; ++j_)                                      \
            bv[j_] = *(const f16x8*)(wsrc + (K0_) * 2 + j_ * 8);            \
    } while (0)

#define STORE_TILE(BUF_) do {                                               \
        f16x8 h0_, l0_, h1_, l1_;                                           \
        cvt_hilo(a0, a1, &h0_, &l0_);                                       \
        cvt_hilo(a2, a3, &h1_, &l1_);                                       \
        *(f16x8*)&Asw[BUF_][arow][((gbase + 0) ^ akey) * 8] = h0_;          \
        *(f16x8*)&Asw[BUF_][arow][((gbase + 1) ^ akey) * 8] = h1_;          \
        *(f16x8*)&Asw[BUF_][arow][((gbase + 4) ^ akey) * 8] = l0_;          \
        *(f16x8*)&Asw[BUF_][arow][((gbase + 5) ^ akey) * 8] = l1_;          \
        _Pragma("unroll")                                                   \
        for (int j_ = 0; j_ < 8; ++j_)                                      \
            *(f16x8*)&Bsw[BUF_][tid][(j_ ^ brot) * 8] = bv[j_];             \
    } while (0)

    LOAD_TILE(0);
    int cur = 0;

    for (int kc = 0; kc < NKC; ++kc) {
        if (cur == 0) STORE_TILE(0); else STORE_TILE(1);   // static LDS indexing
        __syncthreads();

        if (kc + 1 < NKC) LOAD_TILE((kc + 1) * 32);        // overlap with compute

        // fragments + MFMA from buffer `cur`
        f16x8 ah[4], al[4];
        if (cur == 0) {
#pragma unroll
            for (int mi = 0; mi < 4; ++mi) {
                const int r = mi * 16 + fr;
                ah[mi] = *(const f16x8*)&Asw[0][r][((fq + 0) ^ rkey) * 8];
                al[mi] = *(const f16x8*)&Asw[0][r][((fq + 4) ^ rkey) * 8];
            }
#pragma unroll
            for (int ni = 0; ni < 4; ++ni) {
                const int r = wid * 64 + ni * 16 + fr;
                f16x8 bh = *(const f16x8*)&Bsw[0][r][((fq + 0) ^ rkey) * 8];
                f16x8 bl = *(const f16x8*)&Bsw[0][r][((fq + 4) ^ rkey) * 8];
#pragma unroll
                for (int mi = 0; mi < 4; ++mi) {
                    accA[mi][ni] = __builtin_amdgcn_mfma_f32_16x16x32_f16(ah[mi], bh, accA[mi][ni], 0, 0, 0);
                    accB[mi][ni] = __builtin_amdgcn_mfma_f32_16x16x32_f16(ah[mi], bl, accB[mi][ni], 0, 0, 0);
                    accB[mi][ni] = __builtin_amdgcn_mfma_f32_16x16x32_f16(al[mi], bh, accB[mi][ni], 0, 0, 0);
                }
            }
        } else {
#pragma unroll
            for (int mi = 0; mi < 4; ++mi) {
                const int r = mi * 16 + fr;
                ah[mi] = *(const f16x8*)&Asw[1][r][((fq + 0) ^ rkey) * 8];
                al[mi] = *(const f16x8*)&Asw[1][r][((fq + 4) ^ rkey) * 8];
            }
#pragma unroll
            for (int ni = 0; ni < 4; ++ni) {
                const int r = wid * 64 + ni * 16 + fr;
                f16x8 bh = *(const f16x8*)&Bsw[1][r][((fq + 0) ^ rkey) * 8];
                f16x8 bl = *(const f16x8*)&Bsw[1][r][((fq + 4) ^ rkey) * 8];
#pragma unroll
                for (int mi = 0; mi < 4; ++mi) {
                    accA[mi][ni] = __builtin_amdgcn_mfma_f32_16x16x32_f16(ah[mi], bh, accA[mi][ni], 0, 0, 0);
                    accB[mi][ni] = __builtin_amdgcn_mfma_f32_16x16x32_f16(ah[mi], bl, accB[mi][ni], 0, 0, 0);
                    accB[mi][ni] = __builtin_amdgcn_mfma_f32_16x16x32_f16(al[mi], bh, accB[mi][ni], 0, 0, 0);
                }
            }
        }
        cur ^= 1;
    }

    // epilogue: combine, sigmoid, store (C layout: row=(lane>>4)*4+r, col=lane&15)
#pragma unroll
    for (int mi = 0; mi < 4; ++mi)
#pragma unroll
        for (int ni = 0; ni < 4; ++ni) {
            const int e = n0 + wid * 64 + ni * 16 + fr;
#pragma unroll
            for (int r = 0; r < 4; ++r) {
                const int m = m0 + mi * 16 + fq * 4 + r;
                float logit = accA[mi][ni][r] + accB[mi][ni][r] * (1.f / 2048.f);
                S[(size_t)m * NEXP + e] = 1.f / (1.f + expf(-logit));
            }
        }
#undef LOAD_TILE
#undef STORE_TILE
}

// ================= K2: f32 routing + margin flagging =================
__launch_bounds__(256)
__global__ void route_flag_k(const float* __restrict__ S,
                             const float* __restrict__ bias,
                             float* __restrict__ out,
                             int* __restrict__ list,
                             int* __restrict__ count) {
    __shared__ float sraw[4][256];
    const int wv   = threadIdx.x >> 6;
    const int lane = threadIdx.x & 63;
    const int token = blockIdx.x * 4 + wv;
    const float NINF = -__builtin_inff();
    const float PINF =  __builtin_inff();

    const float* row = S + (size_t)token * NEXP;
    float4 v = *(const float4*)(row + lane * 4);
    *(float4*)&sraw[wv][lane * 4] = v;

    const int e0 = lane * 4;
    float4 bi4 = *(const float4*)(bias + e0);
    float b0 = v.x + bi4.x;
    float b1 = v.y + bi4.y;
    float b2 = v.z + bi4.z;
    float b3 = v.w + bi4.w;

    bool flag = false;

    float m1 = b0, m2 = NINF;
    if (b1 > m1) { m2 = m1; m1 = b1; } else if (b1 > m2) m2 = b1;
    if (b2 > m1) { m2 = m1; m1 = b2; } else if (b2 > m2) m2 = b2;
    if (b3 > m1) { m2 = m1; m1 = b3; } else if (b3 > m2) m2 = b3;
#pragma unroll
    for (int w = 1; w <= 4; w <<= 1) {
        float o1 = __shfl_xor(m1, w);
        float o2 = __shfl_xor(m2, w);
        float nm1 = fmaxf(m1, o1);
        float nm2 = fmaxf(fminf(m1, o1), fmaxf(m2, o2));
        m1 = nm1; m2 = nm2;
    }
    const float gs = m1 + m2;
    const int g = lane >> 3;

    int rank = 0;
#pragma unroll
    for (int j = 0; j < 8; ++j) {
        float gj = __shfl(gs, j * 8);
        rank += (gj > gs) || (gj == gs && j < g);
    }
    const bool sel = rank < 4;

    {
        float a = sel ? gs : PINF;
        float b = sel ? NINF : gs;
#pragma unroll
        for (int w = 1; w < 64; w <<= 1) {
            a = fminf(a, __shfl_xor(a, w));
            b = fmaxf(b, __shfl_xor(b, w));
        }
        flag |= (a - b) < 2.f * TAU;
    }

    if (!sel) { b0 = NINF; b1 = NINF; b2 = NINF; b3 = NINF; }

    int myidx = 0;
    float prev = 0.f;
#pragma unroll
    for (int it = 0; it < 9; ++it) {
        float bv = b0; int bi = e0;
        if (b1 > bv) { bv = b1; bi = e0 + 1; }
        if (b2 > bv) { bv = b2; bi = e0 + 2; }
        if (b3 > bv) { bv = b3; bi = e0 + 3; }
#pragma unroll
        for (int w = 1; w < 64; w <<= 1) {
            float ov = __shfl_xor(bv, w);
            int   oi = __shfl_xor(bi, w);
            if (ov > bv || (ov == bv && oi < bi)) { bv = ov; bi = oi; }
        }
        if (it > 0) flag |= (prev - bv) < TAU;
        prev = bv;
        if (it < 8) {
            if (lane == it) myidx = bi;
            if ((bi >> 2) == lane) {
                switch (bi & 3) {
                    case 0: b0 = NINF; break;
                    case 1: b1 = NINF; break;
                    case 2: b2 = NINF; break;
                    case 3: b3 = NINF; break;
                }
            }
        }
    }

    const bool anyflag = __any((int)flag);

    __syncthreads();

    float wval = (lane < 8) ? sraw[wv][myidx] : 0.f;
    float s = wval;
    s += __shfl_xor(s, 1);
    s += __shfl_xor(s, 2);
    s += __shfl_xor(s, 4);
    if (lane < 8) {
        float wout = wval / (s + 1e-20f) * 2.5f;
        out[(size_t)token * 8 + lane] = wout;
        out[(size_t)MTOK * 8 + (size_t)token * 8 + lane] = (float)myidx;
    }

    if (anyflag && lane == 0) {
        int f = atomicAdd(count, 1);
        if (f < CAPR) list[f] = token;
    }
}

// ================= K3: K-split f64 partial GEMM over flagged rows =================
__launch_bounds__(256)
__global__ void rescore_k(const float* __restrict__ X,
                          const float* __restrict__ W,
                          const int* __restrict__ list,
                          const int* __restrict__ count,
                          double* __restrict__ Ldp) {
    const int cnt = min(*count, CAPR);
    const int m0 = blockIdx.x * 64;
    if (m0 >= cnt) return;
    const int n0 = blockIdx.y * 64;
    const int ks = blockIdx.z;
    const int kbase = ks * KCH;

    __shared__ float As[16][66];
    __shared__ float Bs[16][66];
    const int tid = threadIdx.x;
    const int row = tid >> 2;
    const int c   = tid & 3;
    const int tm  = tid >> 4;
    const int tn  = tid & 15;

    const int gi = list[min(m0 + row, cnt - 1)];
    const float* xg = X + (size_t)gi * KDIM + c * 4;
    const float* wg = W + (size_t)(n0 + row) * KDIM + c * 4;

    double acc[4][4];
#pragma unroll
    for (int i = 0; i < 4; ++i)
#pragma unroll
        for (int j = 0; j < 4; ++j) acc[i][j] = 0.0;

    for (int k0 = kbase; k0 < kbase + KCH; k0 += 16) {
        float4 a = *(const float4*)(xg + k0);
        float4 b = *(const float4*)(wg + k0);
        __syncthreads();
        As[c * 4 + 0][row] = a.x; As[c * 4 + 1][row] = a.y;
        As[c * 4 + 2][row] = a.z; As[c * 4 + 3][row] = a.w;
        Bs[c * 4 + 0][row] = b.x; Bs[c * 4 + 1][row] = b.y;
        Bs[c * 4 + 2][row] = b.z; Bs[c * 4 + 3][row] = b.w;
        __syncthreads();
#pragma unroll
        for (int k = 0; k < 16; ++k) {
            double ad[4], bd[4];
#pragma unroll
            for (int i = 0; i < 4; ++i) ad[i] = (double)As[k][tm * 4 + i];
#pragma unroll
            for (int j = 0; j < 4; ++j) bd[j] = (double)Bs[k][tn * 4 + j];
#pragma unroll
            for (int i = 0; i < 4; ++i)
#pragma unroll
                for (int j = 0; j < 4; ++j)
                    acc[i][j] = fma(ad[i], bd[j], acc[i][j]);
        }
    }

#pragma unroll
    for (int i = 0; i < 4; ++i) {
        const int r = m0 + tm * 4 + i;
        if (r < cnt) {
#pragma unroll
            for (int j = 0; j < 4; ++j)
                Ldp[((size_t)ks * CAPR + r) * NEXP + n0 + tn * 4 + j] = acc[i][j];
        }
    }
}

// ================= K4: exact f64 routing for flagged tokens =================
__launch_bounds__(64)
__global__ void route_exact_k(const double* __restrict__ Ldp,
                              const float* __restrict__ bias,
                              const int* __restrict__ list,
                              const int* __restrict__ count,
                              float* __restrict__ out) {
    const int cnt = min(*count, CAPR);
    const int f = blockIdx.x;
    if (f >= cnt) return;
    const int lane = threadIdx.x;
    const int token = list[f];
    const double NINF = -__builtin_inf();

    const int e0 = lane * 4;
    double l0 = 0.0, l1 = 0.0, l2 = 0.0, l3 = 0.0;
#pragma unroll
    for (int s = 0; s < KSPLIT; ++s) {
        double4 p = *(const double4*)(Ldp + ((size_t)s * CAPR + f) * NEXP + e0);
        l0 += p.x; l1 += p.y; l2 += p.z; l3 += p.w;
    }

    double s0 = 1.0 / (1.0 + exp(-l0));
    double s1 = 1.0 / (1.0 + exp(-l1));
    double s2 = 1.0 / (1.0 + exp(-l2));
    double s3 = 1.0 / (1.0 + exp(-l3));

    float4 bi4 = *(const float4*)(bias + e0);
    double b0 = s0 + (double)bi4.x;
    double b1 = s1 + (double)bi4.y;
    double b2 = s2 + (double)bi4.z;
    double b3 = s3 + (double)bi4.w;

    double m1 = b0, m2 = NINF;
    if (b1 > m1) { m2 = m1; m1 = b1; } else if (b1 > m2) m2 = b1;
    if (b2 > m1) { m2 = m1; m1 = b2; } else if (b2 > m2) m2 = b2;
    if (b3 > m1) { m2 = m1; m1 = b3; } else if (b3 > m2) m2 = b3;
#pragma unroll
    for (int w = 1; w <= 4; w <<= 1) {
        double o1 = __shfl_xor(m1, w);
        double o2 = __shfl_xor(m2, w);
        double nm1 = fmax(m1, o1);
        double nm2 = fmax(fmin(m1, o1), fmax(m2, o2));
        m1 = nm1; m2 = nm2;
    }
    const double gs = m1 + m2;
    const int g = lane >> 3;

    int rank = 0;
#pragma unroll
    for (int j = 0; j < 8; ++j) {
        double gj = __shfl(gs, j * 8);
        rank += (gj > gs) || (gj == gs && j < g);
    }
    if (rank >= 4) { b0 = NINF; b1 = NINF; b2 = NINF; b3 = NINF; }

    int myidx = 0;
#pragma unroll
    for (int it = 0; it < 8; ++it) {
        double bv = b0; int bi = e0;
        if (b1 > bv) { bv = b1; bi = e0 + 1; }
        if (b2 > bv) { bv = b2; bi = e0 + 2; }
        if (b3 > bv) { bv = b3; bi = e0 + 3; }
#pragma unroll
        for (int w = 1; w < 64; w <<= 1) {
            double ov = __shfl_xor(bv, w);
            int    oi = __shfl_xor(bi, w);
            if (ov > bv || (ov == bv && oi < bi)) { bv = ov; bi = oi; }
        }
        if (lane == it) myidx = bi;
        if ((bi >> 2) == lane) {
            switch (bi & 3) {
                case 0: b0 = NINF; break;
                case 1: b1 = NINF; break;
                case 2: b2 = NINF; break;
                case 3: b3 = NINF; break;
            }
        }
    }

    double g0 = __shfl(s0, myidx >> 2);
    double g1 = __shfl(s1, myidx >> 2);
    double g2 = __shfl(s2, myidx >> 2);
    double g3 = __shfl(s3, myidx >> 2);
    const int ss = myidx & 3;
    double wval = (lane < 8) ? (ss == 0 ? g0 : ss == 1 ? g1 : ss == 2 ? g2 : g3) : 0.0;
    double s = wval;
    s += __shfl_xor(s, 1);
    s += __shfl_xor(s, 2);
    s += __shfl_xor(s, 4);
    if (lane < 8) {
        float wout = (float)(wval / (s + 1e-20) * 2.5);
        out[(size_t)token * 8 + lane] = wout;
        out[(size_t)MTOK * 8 + (size_t)token * 8 + lane] = (float)myidx;
    }
}

__global__ void init_k(int* count) { *count = 0; }

extern "C" void kernel_launch(void* const* d_in, const int* in_sizes, int n_in,
                              void* d_out, int out_size, void* d_ws, size_t ws_size,
                              hipStream_t stream) {
    const float* X    = (const float*)d_in[0];
    const float* W    = (const float*)d_in[1];
    const float* bias = (const float*)d_in[2];
    float* out = (float*)d_out;

    // ws: [0,16.8MB) Lf f32 scores, later aliased by Ldp f64 partials (rescore
    //     runs after route_flag, when Lf is dead).  Then list, cnt, Wcomb.
    float*  Lf    = (float*)d_ws;
    double* Ldp   = (double*)d_ws;                        // 8*1024*256*8 = 16,777,216 B
    int*    list  = (int*)((char*)d_ws + 16777216);
    int*    cnt   = (int*)((char*)d_ws + 16777216 + CAPR * 4);
    f16*    Wcomb = (f16*)((char*)d_ws + 16777216 + 65536); // 256*14336*2 = 7.34 MB

    init_k<<<1, 1, 0, stream>>>(cnt);
    wconv_k<<<NEXP, NKC, 0, stream>>>(W, Wcomb);

    dim3 g1(NEXP / 128, MTOK / 64);                       // (2, 256)
    gemm_v6_k<<<g1, 128, 0, stream>>>(X, Wcomb, Lf);

    route_flag_k<<<MTOK / 4, 256, 0, stream>>>(Lf, bias, out, list, cnt);

    dim3 g3(CAPR / 64, NEXP / 64, KSPLIT);
    rescore_k<<<g3, 256, 0, stream>>>(X, W, list, cnt, Ldp);

    route_exact_k<<<CAPR, 64, 0, stream>>>(Ldp, bias, list, cnt, out);
}

// Round 7
// 653.153 us; speedup vs baseline: 11.2588x; 2.4688x over previous
//
#include <hip/hip_runtime.h>
#include <math.h>

#define MTOK 16384
#define NEXP 256
#define KDIM 7168

#define CAPR 1024
#define KSPLIT 8
#define KCH (KDIM / KSPLIT)   // 896
#define TAU 2e-5f

#define NKC 224               // K-chunks of 32
// Wfrag layout: [hilo][nt 0..15][kc 0..223][lane 0..63][8 f16]
//   lane = k8*16 + col ; element j -> k = kc*32 + k8*8 + j, expert = nt*16 + col
#define WFRAG_ELEMS ((size_t)2 * 16 * NKC * 512)

typedef _Float16 f16;
typedef __attribute__((ext_vector_type(8))) f16 f16x8;
typedef __attribute__((ext_vector_type(4))) float f32x4;

// ============ K0: W -> Wfrag (MFMA B-fragment order, hi/lo split) ============
__global__ void wconv_k(const float* __restrict__ W, f16* __restrict__ Wfrag) {
    const int e  = blockIdx.x;        // expert 0..255
    const int kc = threadIdx.x;       // 0..223 (256 threads, guard)
    if (kc >= NKC) return;
    const int nt  = e >> 4;
    const int col = e & 15;
    const float* src = W + (size_t)e * KDIM + kc * 32;
    float x[32];
#pragma unroll
    for (int i = 0; i < 8; ++i) {
        float4 v = *(const float4*)(src + i * 4);
        x[i * 4 + 0] = v.x; x[i * 4 + 1] = v.y; x[i * 4 + 2] = v.z; x[i * 4 + 3] = v.w;
    }
#pragma unroll
    for (int k8 = 0; k8 < 4; ++k8) {
        f16x8 h, l;
#pragma unroll
        for (int j = 0; j < 8; ++j) {
            float xv = x[k8 * 8 + j];
            f16 hh = (f16)xv;
            h[j] = hh;
            l[j] = (f16)((xv - (float)hh) * 2048.f);
        }
        const size_t lanepos = (size_t)(k8 * 16 + col) * 8;
        *(f16x8*)(Wfrag + (((size_t)(0 * 16 + nt) * NKC + kc) << 9) + lanepos) = h;
        *(f16x8*)(Wfrag + (((size_t)(1 * 16 + nt) * NKC + kc) << 9) + lanepos) = l;
    }
}

// ============ K1: fp16x2-split MFMA GEMM + sigmoid ============
// BM=64, BN=128; 4 waves (2M x 2N), wave tile 32x64; A via LDS dbuf, B direct global.
__launch_bounds__(256, 2)
__global__ void gemm_v7_k(const float* __restrict__ X,
                          const f16* __restrict__ Wfrag,
                          float* __restrict__ S) {
    __shared__ f16 A_lds[2][2][4][64][8];   // [buf][hilo][k8][row][8] = 16 KB

    const int tid  = threadIdx.x;
    const int lane = tid & 63;
    const int w    = tid >> 6;          // 0..3
    const int wr   = w >> 1;            // M half
    const int wc   = w & 1;             // N half

    // XCD-partitioned block mapping: XCD 0-3 -> n-half 0, XCD 4-7 -> n-half 1
    const int id   = blockIdx.x;        // 0..511
    const int xcd  = id & 7;
    const int slot = id >> 3;           // 0..63
    const int nb   = xcd >> 2;          // 0..1
    const int mb   = slot * 4 + (xcd & 3);  // 0..255
    const int m0 = mb * 64;
    const int n0 = nb * 128;

    // A staging map: thread loads row tid&63, k8-granule tid>>6 (8 f32 = 32 B)
    const int arow = tid & 63;
    const int ak8  = tid >> 6;
    const float* xg = X + (size_t)(m0 + arow) * KDIM + ak8 * 8;

    const int fr = lane & 15;
    const int fq = lane >> 4;

    f32x4 accA[2][4];
    f32x4 accB[2][4];
#pragma unroll
    for (int i = 0; i < 2; ++i)
#pragma unroll
        for (int j = 0; j < 4; ++j) { accA[i][j] = (f32x4)0.f; accB[i][j] = (f32x4)0.f; }

    float4 aA0, aA1, aB0, aB1;          // named prefetch sets (all-static indexing)
    f16x8 bh[4], bl[4];

#define STORE_A(BUF_, R0_, R1_) do {                                        \
        float xs_[8] = {(R0_).x, (R0_).y, (R0_).z, (R0_).w,                 \
                        (R1_).x, (R1_).y, (R1_).z, (R1_).w};                \
        f16x8 h_, l_;                                                       \
        _Pragma("unroll")                                                   \
        for (int e_ = 0; e_ < 8; ++e_) {                                    \
            f16 hh_ = (f16)xs_[e_];                                         \
            h_[e_] = hh_;                                                   \
            l_[e_] = (f16)((xs_[e_] - (float)hh_) * 2048.f);                \
        }                                                                   \
        *(f16x8*)&A_lds[BUF_][0][ak8][arow][0] = h_;                        \
        *(f16x8*)&A_lds[BUF_][1][ak8][arow][0] = l_;                        \
    } while (0)

#define B_LOADS(KC_) do {                                                   \
        _Pragma("unroll")                                                   \
        for (int ni_ = 0; ni_ < 4; ++ni_) {                                 \
            const size_t nt_ = (size_t)(nb * 8 + wc * 4 + ni_);             \
            bh[ni_] = *(const f16x8*)(Wfrag + (((nt_)      * NKC + (KC_)) << 9) + lane * 8); \
            bl[ni_] = *(const f16x8*)(Wfrag + (((nt_ + 16) * NKC + (KC_)) << 9) + lane * 8); \
        }                                                                   \
    } while (0)

#define COMPUTE(BUF_) do {                                                  \
        f16x8 ah_[2], al_[2];                                               \
        _Pragma("unroll")                                                   \
        for (int mi_ = 0; mi_ < 2; ++mi_) {                                 \
            const int r_ = wr * 32 + mi_ * 16 + fr;                         \
            ah_[mi_] = *(const f16x8*)&A_lds[BUF_][0][fq][r_][0];           \
            al_[mi_] = *(const f16x8*)&A_lds[BUF_][1][fq][r_][0];           \
        }                                                                   \
        _Pragma("unroll")                                                   \
        for (int ni_ = 0; ni_ < 4; ++ni_) {                                 \
            _Pragma("unroll")                                               \
            for (int mi_ = 0; mi_ < 2; ++mi_) {                             \
                accA[mi_][ni_] = __builtin_amdgcn_mfma_f32_16x16x32_f16(ah_[mi_], bh[ni_], accA[mi_][ni_], 0, 0, 0); \
                accB[mi_][ni_] = __builtin_amdgcn_mfma_f32_16x16x32_f16(ah_[mi_], bl[ni_], accB[mi_][ni_], 0, 0, 0); \
                accB[mi_][ni_] = __builtin_amdgcn_mfma_f32_16x16x32_f16(al_[mi_], bh[ni_], accB[mi_][ni_], 0, 0, 0); \
            }                                                               \
        }                                                                   \
    } while (0)

    // prologue
    aA0 = *(const float4*)(xg + 0);
    aA1 = *(const float4*)(xg + 4);

    for (int kc = 0; kc < NKC; kc += 2) {
        // ---- even half: buf 0, consumes regs A, prefetches regs B (kc+1) ----
        STORE_A(0, aA0, aA1);
        __syncthreads();
        aB0 = *(const float4*)(xg + (kc + 1) * 32 + 0);   // kc+1 <= 223 always
        aB1 = *(const float4*)(xg + (kc + 1) * 32 + 4);
        B_LOADS(kc);
        COMPUTE(0);

        // ---- odd half: buf 1, consumes regs B, prefetches regs A (kc+2) ----
        STORE_A(1, aB0, aB1);
        __syncthreads();
        if (kc + 2 < NKC) {
            aA0 = *(const float4*)(xg + (kc + 2) * 32 + 0);
            aA1 = *(const float4*)(xg + (kc + 2) * 32 + 4);
        }
        B_LOADS(kc + 1);
        COMPUTE(1);
    }

    // epilogue: combine, sigmoid, store (C layout: row=(lane>>4)*4+r, col=lane&15)
#pragma unroll
    for (int mi = 0; mi < 2; ++mi)
#pragma unroll
        for (int ni = 0; ni < 4; ++ni) {
            const int e = n0 + wc * 64 + ni * 16 + fr;
#pragma unroll
            for (int r = 0; r < 4; ++r) {
                const int m = m0 + wr * 32 + mi * 16 + fq * 4 + r;
                float logit = accA[mi][ni][r] + accB[mi][ni][r] * (1.f / 2048.f);
                S[(size_t)m * NEXP + e] = 1.f / (1.f + expf(-logit));
            }
        }
#undef STORE_A
#undef B_LOADS
#undef COMPUTE
}

// ================= K2: f32 routing + margin flagging =================
__launch_bounds__(256)
__global__ void route_flag_k(const float* __restrict__ S,
                             const float* __restrict__ bias,
                             float* __restrict__ out,
                             int* __restrict__ list,
                             int* __restrict__ count) {
    __shared__ float sraw[4][256];
    const int wv   = threadIdx.x >> 6;
    const int lane = threadIdx.x & 63;
    const int token = blockIdx.x * 4 + wv;
    const float NINF = -__builtin_inff();
    const float PINF =  __builtin_inff();

    const float* row = S + (size_t)token * NEXP;
    float4 v = *(const float4*)(row + lane * 4);
    *(float4*)&sraw[wv][lane * 4] = v;

    const int e0 = lane * 4;
    float4 bi4 = *(const float4*)(bias + e0);
    float b0 = v.x + bi4.x;
    float b1 = v.y + bi4.y;
    float b2 = v.z + bi4.z;
    float b3 = v.w + bi4.w;

    bool flag = false;

    float m1 = b0, m2 = NINF;
    if (b1 > m1) { m2 = m1; m1 = b1; } else if (b1 > m2) m2 = b1;
    if (b2 > m1) { m2 = m1; m1 = b2; } else if (b2 > m2) m2 = b2;
    if (b3 > m1) { m2 = m1; m1 = b3; } else if (b3 > m2) m2 = b3;
#pragma unroll
    for (int w = 1; w <= 4; w <<= 1) {
        float o1 = __shfl_xor(m1, w);
        float o2 = __shfl_xor(m2, w);
        float nm1 = fmaxf(m1, o1);
        float nm2 = fmaxf(fminf(m1, o1), fmaxf(m2, o2));
        m1 = nm1; m2 = nm2;
    }
    const float gs = m1 + m2;
    const int g = lane >> 3;

    int rank = 0;
#pragma unroll
    for (int j = 0; j < 8; ++j) {
        float gj = __shfl(gs, j * 8);
        rank += (gj > gs) || (gj == gs && j < g);
    }
    const bool sel = rank < 4;

    {
        float a = sel ? gs : PINF;
        float b = sel ? NINF : gs;
#pragma unroll
        for (int w = 1; w < 64; w <<= 1) {
            a = fminf(a, __shfl_xor(a, w));
            b = fmaxf(b, __shfl_xor(b, w));
        }
        flag |= (a - b) < 2.f * TAU;
    }

    if (!sel) { b0 = NINF; b1 = NINF; b2 = NINF; b3 = NINF; }

    int myidx = 0;
    float prev = 0.f;
#pragma unroll
    for (int it = 0; it < 9; ++it) {
        float bv = b0; int bi = e0;
        if (b1 > bv) { bv = b1; bi = e0 + 1; }
        if (b2 > bv) { bv = b2; bi = e0 + 2; }
        if (b3 > bv) { bv = b3; bi = e0 + 3; }
#pragma unroll
        for (int w = 1; w < 64; w <<= 1) {
            float ov = __shfl_xor(bv, w);
            int   oi = __shfl_xor(bi, w);
            if (ov > bv || (ov == bv && oi < bi)) { bv = ov; bi = oi; }
        }
        if (it > 0) flag |= (prev - bv) < TAU;
        prev = bv;
        if (it < 8) {
            if (lane == it) myidx = bi;
            if ((bi >> 2) == lane) {
                switch (bi & 3) {
                    case 0: b0 = NINF; break;
                    case 1: b1 = NINF; break;
                    case 2: b2 = NINF; break;
                    case 3: b3 = NINF; break;
                }
            }
        }
    }

    const bool anyflag = __any((int)flag);

    __syncthreads();

    float wval = (lane < 8) ? sraw[wv][myidx] : 0.f;
    float s = wval;
    s += __shfl_xor(s, 1);
    s += __shfl_xor(s, 2);
    s += __shfl_xor(s, 4);
    if (lane < 8) {
        float wout = wval / (s + 1e-20f) * 2.5f;
        out[(size_t)token * 8 + lane] = wout;
        out[(size_t)MTOK * 8 + (size_t)token * 8 + lane] = (float)myidx;
    }

    if (anyflag && lane == 0) {
        int f = atomicAdd(count, 1);
        if (f < CAPR) list[f] = token;
    }
}

// ================= K3: K-split f64 partial GEMM over flagged rows =================
__launch_bounds__(256)
__global__ void rescore_k(const float* __restrict__ X,
                          const float* __restrict__ W,
                          const int* __restrict__ list,
                          const int* __restrict__ count,
                          double* __restrict__ Ldp) {
    const int cnt = min(*count, CAPR);
    const int m0 = blockIdx.x * 64;
    if (m0 >= cnt) return;
    const int n0 = blockIdx.y * 64;
    const int ks = blockIdx.z;
    const int kbase = ks * KCH;

    __shared__ float As[16][66];
    __shared__ float Bs[16][66];
    const int tid = threadIdx.x;
    const int row = tid >> 2;
    const int c   = tid & 3;
    const int tm  = tid >> 4;
    const int tn  = tid & 15;

    const int gi = list[min(m0 + row, cnt - 1)];
    const float* xg = X + (size_t)gi * KDIM + c * 4;
    const float* wg = W + (size_t)(n0 + row) * KDIM + c * 4;

    double acc[4][4];
#pragma unroll
    for (int i = 0; i < 4; ++i)
#pragma unroll
        for (int j = 0; j < 4; ++j) acc[i][j] = 0.0;

    for (int k0 = kbase; k0 < kbase + KCH; k0 += 16) {
        float4 a = *(const float4*)(xg + k0);
        float4 b = *(const float4*)(wg + k0);
        __syncthreads();
        As[c * 4 + 0][row] = a.x; As[c * 4 + 1][row] = a.y;
        As[c * 4 + 2][row] = a.z; As[c * 4 + 3][row] = a.w;
        Bs[c * 4 + 0][row] = b.x; Bs[c * 4 + 1][row] = b.y;
        Bs[c * 4 + 2][row] = b.z; Bs[c * 4 + 3][row] = b.w;
        __syncthreads();
#pragma unroll
        for (int k = 0; k < 16; ++k) {
            double ad[4], bd[4];
#pragma unroll
            for (int i = 0; i < 4; ++i) ad[i] = (double)As[k][tm * 4 + i];
#pragma unroll
            for (int j = 0; j < 4; ++j) bd[j] = (double)Bs[k][tn * 4 + j];
#pragma unroll
            for (int i = 0; i < 4; ++i)
#pragma unroll
                for (int j = 0; j < 4; ++j)
                    acc[i][j] = fma(ad[i], bd[j], acc[i][j]);
        }
    }

#pragma unroll
    for (int i = 0; i < 4; ++i) {
        const int r = m0 + tm * 4 + i;
        if (r < cnt) {
#pragma unroll
            for (int j = 0; j < 4; ++j)
                Ldp[((size_t)ks * CAPR + r) * NEXP + n0 + tn * 4 + j] = acc[i][j];
        }
    }
}

// ================= K4: exact f64 routing for flagged tokens =================
__launch_bounds__(64)
__global__ void route_exact_k(const double* __restrict__ Ldp,
                              const float* __restrict__ bias,
                              const int* __restrict__ list,
                              const int* __restrict__ count,
                              float* __restrict__ out) {
    const int cnt = min(*count, CAPR);
    const int f = blockIdx.x;
    if (f >= cnt) return;
    const int lane = threadIdx.x;
    const int token = list[f];
    const double NINF = -__builtin_inf();

    const int e0 = lane * 4;
    double l0 = 0.0, l1 = 0.0, l2 = 0.0, l3 = 0.0;
#pragma unroll
    for (int s = 0; s < KSPLIT; ++s) {
        double4 p = *(const double4*)(Ldp + ((size_t)s * CAPR + f) * NEXP + e0);
        l0 += p.x; l1 += p.y; l2 += p.z; l3 += p.w;
    }

    double s0 = 1.0 / (1.0 + exp(-l0));
    double s1 = 1.0 / (1.0 + exp(-l1));
    double s2 = 1.0 / (1.0 + exp(-l2));
    double s3 = 1.0 / (1.0 + exp(-l3));

    float4 bi4 = *(const float4*)(bias + e0);
    double b0 = s0 + (double)bi4.x;
    double b1 = s1 + (double)bi4.y;
    double b2 = s2 + (double)bi4.z;
    double b3 = s3 + (double)bi4.w;

    double m1 = b0, m2 = NINF;
    if (b1 > m1) { m2 = m1; m1 = b1; } else if (b1 > m2) m2 = b1;
    if (b2 > m1) { m2 = m1; m1 = b2; } else if (b2 > m2) m2 = b2;
    if (b3 > m1) { m2 = m1; m1 = b3; } else if (b3 > m2) m2 = b3;
#pragma unroll
    for (int w = 1; w <= 4; w <<= 1) {
        double o1 = __shfl_xor(m1, w);
        double o2 = __shfl_xor(m2, w);
        double nm1 = fmax(m1, o1);
        double nm2 = fmax(fmin(m1, o1), fmax(m2, o2));
        m1 = nm1; m2 = nm2;
    }
    const double gs = m1 + m2;
    const int g = lane >> 3;

    int rank = 0;
#pragma unroll
    for (int j = 0; j < 8; ++j) {
        double gj = __shfl(gs, j * 8);
        rank += (gj > gs) || (gj == gs && j < g);
    }
    if (rank >= 4) { b0 = NINF; b1 = NINF; b2 = NINF; b3 = NINF; }

    int myidx = 0;
#pragma unroll
    for (int it = 0; it < 8; ++it) {
        double bv = b0; int bi = e0;
        if (b1 > bv) { bv = b1; bi = e0 + 1; }
        if (b2 > bv) { bv = b2; bi = e0 + 2; }
        if (b3 > bv) { bv = b3; bi = e0 + 3; }
#pragma unroll
        for (int w = 1; w < 64; w <<= 1) {
            double ov = __shfl_xor(bv, w);
            int    oi = __shfl_xor(bi, w);
            if (ov > bv || (ov == bv && oi < bi)) { bv = ov; bi = oi; }
        }
        if (lane == it) myidx = bi;
        if ((bi >> 2) == lane) {
            switch (bi & 3) {
                case 0: b0 = NINF; break;
                case 1: b1 = NINF; break;
                case 2: b2 = NINF; break;
                case 3: b3 = NINF; break;
            }
        }
    }

    double g0 = __shfl(s0, myidx >> 2);
    double g1 = __shfl(s1, myidx >> 2);
    double g2 = __shfl(s2, myidx >> 2);
    double g3 = __shfl(s3, myidx >> 2);
    const int ss = myidx & 3;
    double wval = (lane < 8) ? (ss == 0 ? g0 : ss == 1 ? g1 : ss == 2 ? g2 : g3) : 0.0;
    double s = wval;
    s += __shfl_xor(s, 1);
    s += __shfl_xor(s, 2);
    s += __shfl_xor(s, 4);
    if (lane < 8) {
        float wout = (float)(wval / (s + 1e-20) * 2.5);
        out[(size_t)token * 8 + lane] = wout;
        out[(size_t)MTOK * 8 + (size_t)token * 8 + lane] = (float)myidx;
    }
}

__global__ void init_k(int* count) { *count = 0; }

extern "C" void kernel_launch(void* const* d_in, const int* in_sizes, int n_in,
                              void* d_out, int out_size, void* d_ws, size_t ws_size,
                              hipStream_t stream) {
    const float* X    = (const float*)d_in[0];
    const float* W    = (const float*)d_in[1];
    const float* bias = (const float*)d_in[2];
    float* out = (float*)d_out;

    // ws: [0,16.8MB) Lf f32 scores, later aliased by Ldp f64 partials (rescore
    //     runs after route_flag, when Lf is dead). Then list, cnt, Wfrag.
    float*  Lf    = (float*)d_ws;
    double* Ldp   = (double*)d_ws;                        // 8*1024*256*8 = 16,777,216 B
    int*    list  = (int*)((char*)d_ws + 16777216);
    int*    cnt   = (int*)((char*)d_ws + 16777216 + CAPR * 4);
    f16*    Wfrag = (f16*)((char*)d_ws + 16777216 + 65536); // 7,340,032 B

    init_k<<<1, 1, 0, stream>>>(cnt);
    wconv_k<<<NEXP, 256, 0, stream>>>(W, Wfrag);

    gemm_v7_k<<<512, 256, 0, stream>>>(X, Wfrag, Lf);

    route_flag_k<<<MTOK / 4, 256, 0, stream>>>(Lf, bias, out, list, cnt);

    dim3 g3(CAPR / 64, NEXP / 64, KSPLIT);
    rescore_k<<<g3, 256, 0, stream>>>(X, W, list, cnt, Ldp);

    route_exact_k<<<CAPR, 64, 0, stream>>>(Ldp, bias, list, cnt, out);
}

// Round 8
// 512.096 us; speedup vs baseline: 14.3601x; 1.2755x over previous
//
#include <hip/hip_runtime.h>
#include <math.h>

#define MTOK 16384
#define NEXP 256
#define KDIM 7168

#define CAPR 1024
#define KSPLIT 8
#define KCH (KDIM / KSPLIT)   // 896
#define TAU 2e-5f

#define NKC 224               // K-chunks of 32
// Wfrag layout: [hilo][nt 0..15][kc 0..223][lane 0..63][8 f16]
//   lane = k8*16 + col ; element j -> k = kc*32 + k8*8 + j, expert = nt*16 + col

typedef _Float16 f16;
typedef __attribute__((ext_vector_type(8))) f16 f16x8;
typedef __attribute__((ext_vector_type(4))) float f32x4;

// ============ K0: W -> Wfrag (MFMA B-fragment order, hi/lo split) ============
__global__ void wconv_k(const float* __restrict__ W, f16* __restrict__ Wfrag) {
    const int e  = blockIdx.x;        // expert 0..255
    const int kc = threadIdx.x;       // 0..223 (256 threads, guard)
    if (kc >= NKC) return;
    const int nt  = e >> 4;
    const int col = e & 15;
    const float* src = W + (size_t)e * KDIM + kc * 32;
    float x[32];
#pragma unroll
    for (int i = 0; i < 8; ++i) {
        float4 v = *(const float4*)(src + i * 4);
        x[i * 4 + 0] = v.x; x[i * 4 + 1] = v.y; x[i * 4 + 2] = v.z; x[i * 4 + 3] = v.w;
    }
#pragma unroll
    for (int k8 = 0; k8 < 4; ++k8) {
        f16x8 h, l;
#pragma unroll
        for (int j = 0; j < 8; ++j) {
            float xv = x[k8 * 8 + j];
            f16 hh = (f16)xv;
            h[j] = hh;
            l[j] = (f16)((xv - (float)hh) * 2048.f);
        }
        const size_t lanepos = (size_t)(k8 * 16 + col) * 8;
        *(f16x8*)(Wfrag + (((size_t)(0 * 16 + nt) * NKC + kc) << 9) + lanepos) = h;
        *(f16x8*)(Wfrag + (((size_t)(1 * 16 + nt) * NKC + kc) << 9) + lanepos) = l;
    }
}

// ============ K1: fp16x2-split MFMA GEMM + sigmoid ============
// BM=64, BN=128; 8 waves (2M x 4N), wave tile 32x32; A via LDS dbuf (tid<256
// stages, v7-proven layout), B direct global with register double-buffer,
// A prefetch distance 2 phases. All register indexing static.
__launch_bounds__(512, 4)
__global__ void gemm_v8_k(const float* __restrict__ X,
                          const f16* __restrict__ Wfrag,
                          float* __restrict__ S) {
    __shared__ f16 A_lds[2][2][4][64][8];   // [buf][hilo][k8][row][8] = 16 KB

    const int tid  = threadIdx.x;
    const int lane = tid & 63;
    const int w    = tid >> 6;          // 0..7
    const int wr   = w >> 2;            // 0..1 (M half)
    const int wc   = w & 3;             // 0..3 (N quarter of the half)

    // XCD-partitioned block mapping: XCD 0-3 -> n-half 0, XCD 4-7 -> n-half 1
    const int id   = blockIdx.x;        // 0..511
    const int xcd  = id & 7;
    const int slot = id >> 3;           // 0..63
    const int nb   = xcd >> 2;          // 0..1
    const int mb   = slot * 4 + (xcd & 3);  // 0..255
    const int m0 = mb * 64;
    const int n0 = nb * 128;

    // A staging map (tid < 256 only): row tid&63, k8-granule (tid>>6)&3
    const int arow = tid & 63;
    const int ak8  = (tid >> 6) & 3;
    const float* xg = X + (size_t)(m0 + arow) * KDIM + ak8 * 8;
    const bool stager = (tid < 256);

    const int fr = lane & 15;
    const int fq = lane >> 4;

    // B fragment bases for this wave: nt = nb*8 + wc*2 + {0,1}; lo at nt+16
    const int ntb = nb * 8 + wc * 2;
    const f16* wpH0 = Wfrag + (((size_t)(ntb + 0)  * NKC) << 9) + lane * 8;
    const f16* wpH1 = Wfrag + (((size_t)(ntb + 1)  * NKC) << 9) + lane * 8;
    const f16* wpL0 = Wfrag + (((size_t)(ntb + 16) * NKC) << 9) + lane * 8;
    const f16* wpL1 = Wfrag + (((size_t)(ntb + 17) * NKC) << 9) + lane * 8;

    f32x4 accA[2][2];
    f32x4 accB[2][2];
#pragma unroll
    for (int i = 0; i < 2; ++i)
#pragma unroll
        for (int j = 0; j < 2; ++j) { accA[i][j] = (f32x4)0.f; accB[i][j] = (f32x4)0.f; }

    float4 aE0, aE1, aO0, aO1;          // A prefetch, two named sets (distance 2)
    f16x8 b0H0, b0H1, b0L0, b0L1;       // B set 0
    f16x8 b1H0, b1H1, b1L0, b1L1;       // B set 1

#define A_LOAD(R0_, R1_, KC_) do { if (stager) {                            \
        R0_ = *(const float4*)(xg + (size_t)(KC_) * 32);                    \
        R1_ = *(const float4*)(xg + (size_t)(KC_) * 32 + 4);                \
    } } while (0)

#define B_LOAD(H0_, H1_, L0_, L1_, KC_) do {                                \
        const size_t ko_ = ((size_t)(KC_)) << 9;                            \
        H0_ = *(const f16x8*)(wpH0 + ko_);                                  \
        H1_ = *(const f16x8*)(wpH1 + ko_);                                  \
        L0_ = *(const f16x8*)(wpL0 + ko_);                                  \
        L1_ = *(const f16x8*)(wpL1 + ko_);                                  \
    } while (0)

#define STORE_A(BUF_, R0_, R1_) do { if (stager) {                          \
        float xs_[8] = {(R0_).x, (R0_).y, (R0_).z, (R0_).w,                 \
                        (R1_).x, (R1_).y, (R1_).z, (R1_).w};                \
        f16x8 h_, l_;                                                       \
        _Pragma("unroll")                                                   \
        for (int e_ = 0; e_ < 8; ++e_) {                                    \
            f16 hh_ = (f16)xs_[e_];                                         \
            h_[e_] = hh_;                                                   \
            l_[e_] = (f16)((xs_[e_] - (float)hh_) * 2048.f);                \
        }                                                                   \
        *(f16x8*)&A_lds[BUF_][0][ak8][arow][0] = h_;                        \
        *(f16x8*)&A_lds[BUF_][1][ak8][arow][0] = l_;                        \
    } } while (0)

#define MFMA16(A_, B_, C_) __builtin_amdgcn_mfma_f32_16x16x32_f16(A_, B_, C_, 0, 0, 0)

#define COMPUTE(BUF_, H0_, H1_, L0_, L1_) do {                              \
        f16x8 ah0_ = *(const f16x8*)&A_lds[BUF_][0][fq][wr * 32 +      fr][0]; \
        f16x8 ah1_ = *(const f16x8*)&A_lds[BUF_][0][fq][wr * 32 + 16 + fr][0]; \
        f16x8 al0_ = *(const f16x8*)&A_lds[BUF_][1][fq][wr * 32 +      fr][0]; \
        f16x8 al1_ = *(const f16x8*)&A_lds[BUF_][1][fq][wr * 32 + 16 + fr][0]; \
        accA[0][0] = MFMA16(ah0_, H0_, accA[0][0]);                         \
        accA[1][0] = MFMA16(ah1_, H0_, accA[1][0]);                         \
        accA[0][1] = MFMA16(ah0_, H1_, accA[0][1]);                         \
        accA[1][1] = MFMA16(ah1_, H1_, accA[1][1]);                         \
        accB[0][0] = MFMA16(ah0_, L0_, accB[0][0]);                         \
        accB[0][0] = MFMA16(al0_, H0_, accB[0][0]);                         \
        accB[1][0] = MFMA16(ah1_, L0_, accB[1][0]);                         \
        accB[1][0] = MFMA16(al1_, H0_, accB[1][0]);                         \
        accB[0][1] = MFMA16(ah0_, L1_, accB[0][1]);                         \
        accB[0][1] = MFMA16(al0_, H1_, accB[0][1]);                         \
        accB[1][1] = MFMA16(ah1_, L1_, accB[1][1]);                         \
        accB[1][1] = MFMA16(al1_, H1_, accB[1][1]);                         \
    } while (0)

    // prologue: aE=A(0), aO=A(1), b0=B(0)
    A_LOAD(aE0, aE1, 0);
    A_LOAD(aO0, aO1, 1);
    B_LOAD(b0H0, b0H1, b0L0, b0L1, 0);

    for (int kc = 0; kc < NKC; kc += 2) {
        // ---- even phase: buf0, A(kc), B set0 ----
        STORE_A(0, aE0, aE1);
        __syncthreads();
        {
            const int kn = (kc + 2 < NKC) ? kc + 2 : kc;   // clamp (tail harmless)
            A_LOAD(aE0, aE1, kn);
        }
        B_LOAD(b1H0, b1H1, b1L0, b1L1, kc + 1);            // kc+1 <= 223 always
        COMPUTE(0, b0H0, b0H1, b0L0, b0L1);

        // ---- odd phase: buf1, A(kc+1), B set1 ----
        STORE_A(1, aO0, aO1);
        __syncthreads();
        {
            const int kn = (kc + 3 < NKC) ? kc + 3 : kc + 1;
            A_LOAD(aO0, aO1, kn);
        }
        {
            const int kn = (kc + 2 < NKC) ? kc + 2 : kc;
            B_LOAD(b0H0, b0H1, b0L0, b0L1, kn);
        }
        COMPUTE(1, b1H0, b1H1, b1L0, b1L1);
    }

    // epilogue: combine, sigmoid, store (C layout: row=(lane>>4)*4+r, col=lane&15)
#pragma unroll
    for (int mi = 0; mi < 2; ++mi)
#pragma unroll
        for (int ni = 0; ni < 2; ++ni) {
            const int e = n0 + wc * 32 + ni * 16 + fr;
#pragma unroll
            for (int r = 0; r < 4; ++r) {
                const int m = m0 + wr * 32 + mi * 16 + fq * 4 + r;
                float logit = accA[mi][ni][r] + accB[mi][ni][r] * (1.f / 2048.f);
                S[(size_t)m * NEXP + e] = 1.f / (1.f + expf(-logit));
            }
        }
#undef A_LOAD
#undef B_LOAD
#undef STORE_A
#undef MFMA16
#undef COMPUTE
}

// ================= K2: f32 routing + margin flagging =================
__launch_bounds__(256)
__global__ void route_flag_k(const float* __restrict__ S,
                             const float* __restrict__ bias,
                             float* __restrict__ out,
                             int* __restrict__ list,
                             int* __restrict__ count) {
    __shared__ float sraw[4][256];
    const int wv   = threadIdx.x >> 6;
    const int lane = threadIdx.x & 63;
    const int token = blockIdx.x * 4 + wv;
    const float NINF = -__builtin_inff();
    const float PINF =  __builtin_inff();

    const float* row = S + (size_t)token * NEXP;
    float4 v = *(const float4*)(row + lane * 4);
    *(float4*)&sraw[wv][lane * 4] = v;

    const int e0 = lane * 4;
    float4 bi4 = *(const float4*)(bias + e0);
    float b0 = v.x + bi4.x;
    float b1 = v.y + bi4.y;
    float b2 = v.z + bi4.z;
    float b3 = v.w + bi4.w;

    bool flag = false;

    float m1 = b0, m2 = NINF;
    if (b1 > m1) { m2 = m1; m1 = b1; } else if (b1 > m2) m2 = b1;
    if (b2 > m1) { m2 = m1; m1 = b2; } else if (b2 > m2) m2 = b2;
    if (b3 > m1) { m2 = m1; m1 = b3; } else if (b3 > m2) m2 = b3;
#pragma unroll
    for (int w = 1; w <= 4; w <<= 1) {
        float o1 = __shfl_xor(m1, w);
        float o2 = __shfl_xor(m2, w);
        float nm1 = fmaxf(m1, o1);
        float nm2 = fmaxf(fminf(m1, o1), fmaxf(m2, o2));
        m1 = nm1; m2 = nm2;
    }
    const float gs = m1 + m2;
    const int g = lane >> 3;

    int rank = 0;
#pragma unroll
    for (int j = 0; j < 8; ++j) {
        float gj = __shfl(gs, j * 8);
        rank += (gj > gs) || (gj == gs && j < g);
    }
    const bool sel = rank < 4;

    {
        float a = sel ? gs : PINF;
        float b = sel ? NINF : gs;
#pragma unroll
        for (int w = 1; w < 64; w <<= 1) {
            a = fminf(a, __shfl_xor(a, w));
            b = fmaxf(b, __shfl_xor(b, w));
        }
        flag |= (a - b) < 2.f * TAU;
    }

    if (!sel) { b0 = NINF; b1 = NINF; b2 = NINF; b3 = NINF; }

    int myidx = 0;
    float prev = 0.f;
#pragma unroll
    for (int it = 0; it < 9; ++it) {
        float bv = b0; int bi = e0;
        if (b1 > bv) { bv = b1; bi = e0 + 1; }
        if (b2 > bv) { bv = b2; bi = e0 + 2; }
        if (b3 > bv) { bv = b3; bi = e0 + 3; }
#pragma unroll
        for (int w = 1; w < 64; w <<= 1) {
            float ov = __shfl_xor(bv, w);
            int   oi = __shfl_xor(bi, w);
            if (ov > bv || (ov == bv && oi < bi)) { bv = ov; bi = oi; }
        }
        if (it > 0) flag |= (prev - bv) < TAU;
        prev = bv;
        if (it < 8) {
            if (lane == it) myidx = bi;
            if ((bi >> 2) == lane) {
                switch (bi & 3) {
                    case 0: b0 = NINF; break;
                    case 1: b1 = NINF; break;
                    case 2: b2 = NINF; break;
                    case 3: b3 = NINF; break;
                }
            }
        }
    }

    const bool anyflag = __any((int)flag);

    __syncthreads();

    float wval = (lane < 8) ? sraw[wv][myidx] : 0.f;
    float s = wval;
    s += __shfl_xor(s, 1);
    s += __shfl_xor(s, 2);
    s += __shfl_xor(s, 4);
    if (lane < 8) {
        float wout = wval / (s + 1e-20f) * 2.5f;
        out[(size_t)token * 8 + lane] = wout;
        out[(size_t)MTOK * 8 + (size_t)token * 8 + lane] = (float)myidx;
    }

    if (anyflag && lane == 0) {
        int f = atomicAdd(count, 1);
        if (f < CAPR) list[f] = token;
    }
}

// ================= K3: K-split f64 partial GEMM over flagged rows =================
__launch_bounds__(256)
__global__ void rescore_k(const float* __restrict__ X,
                          const float* __restrict__ W,
                          const int* __restrict__ list,
                          const int* __restrict__ count,
                          double* __restrict__ Ldp) {
    const int cnt = min(*count, CAPR);
    const int m0 = blockIdx.x * 64;
    if (m0 >= cnt) return;
    const int n0 = blockIdx.y * 64;
    const int ks = blockIdx.z;
    const int kbase = ks * KCH;

    __shared__ float As[16][66];
    __shared__ float Bs[16][66];
    const int tid = threadIdx.x;
    const int row = tid >> 2;
    const int c   = tid & 3;
    const int tm  = tid >> 4;
    const int tn  = tid & 15;

    const int gi = list[min(m0 + row, cnt - 1)];
    const float* xg = X + (size_t)gi * KDIM + c * 4;
    const float* wg = W + (size_t)(n0 + row) * KDIM + c * 4;

    double acc[4][4];
#pragma unroll
    for (int i = 0; i < 4; ++i)
#pragma unroll
        for (int j = 0; j < 4; ++j) acc[i][j] = 0.0;

    for (int k0 = kbase; k0 < kbase + KCH; k0 += 16) {
        float4 a = *(const float4*)(xg + k0);
        float4 b = *(const float4*)(wg + k0);
        __syncthreads();
        As[c * 4 + 0][row] = a.x; As[c * 4 + 1][row] = a.y;
        As[c * 4 + 2][row] = a.z; As[c * 4 + 3][row] = a.w;
        Bs[c * 4 + 0][row] = b.x; Bs[c * 4 + 1][row] = b.y;
        Bs[c * 4 + 2][row] = b.z; Bs[c * 4 + 3][row] = b.w;
        __syncthreads();
#pragma unroll
        for (int k = 0; k < 16; ++k) {
            double ad[4], bd[4];
#pragma unroll
            for (int i = 0; i < 4; ++i) ad[i] = (double)As[k][tm * 4 + i];
#pragma unroll
            for (int j = 0; j < 4; ++j) bd[j] = (double)Bs[k][tn * 4 + j];
#pragma unroll
            for (int i = 0; i < 4; ++i)
#pragma unroll
                for (int j = 0; j < 4; ++j)
                    acc[i][j] = fma(ad[i], bd[j], acc[i][j]);
        }
    }

#pragma unroll
    for (int i = 0; i < 4; ++i) {
        const int r = m0 + tm * 4 + i;
        if (r < cnt) {
#pragma unroll
            for (int j = 0; j < 4; ++j)
                Ldp[((size_t)ks * CAPR + r) * NEXP + n0 + tn * 4 + j] = acc[i][j];
        }
    }
}

// ================= K4: exact f64 routing for flagged tokens =================
__launch_bounds__(64)
__global__ void route_exact_k(const double* __restrict__ Ldp,
                              const float* __restrict__ bias,
                              const int* __restrict__ list,
                              const int* __restrict__ count,
                              float* __restrict__ out) {
    const int cnt = min(*count, CAPR);
    const int f = blockIdx.x;
    if (f >= cnt) return;
    const int lane = threadIdx.x;
    const int token = list[f];
    const double NINF = -__builtin_inf();

    const int e0 = lane * 4;
    double l0 = 0.0, l1 = 0.0, l2 = 0.0, l3 = 0.0;
#pragma unroll
    for (int s = 0; s < KSPLIT; ++s) {
        double4 p = *(const double4*)(Ldp + ((size_t)s * CAPR + f) * NEXP + e0);
        l0 += p.x; l1 += p.y; l2 += p.z; l3 += p.w;
    }

    double s0 = 1.0 / (1.0 + exp(-l0));
    double s1 = 1.0 / (1.0 + exp(-l1));
    double s2 = 1.0 / (1.0 + exp(-l2));
    double s3 = 1.0 / (1.0 + exp(-l3));

    float4 bi4 = *(const float4*)(bias + e0);
    double b0 = s0 + (double)bi4.x;
    double b1 = s1 + (double)bi4.y;
    double b2 = s2 + (double)bi4.z;
    double b3 = s3 + (double)bi4.w;

    double m1 = b0, m2 = NINF;
    if (b1 > m1) { m2 = m1; m1 = b1; } else if (b1 > m2) m2 = b1;
    if (b2 > m1) { m2 = m1; m1 = b2; } else if (b2 > m2) m2 = b2;
    if (b3 > m1) { m2 = m1; m1 = b3; } else if (b3 > m2) m2 = b3;
#pragma unroll
    for (int w = 1; w <= 4; w <<= 1) {
        double o1 = __shfl_xor(m1, w);
        double o2 = __shfl_xor(m2, w);
        double nm1 = fmax(m1, o1);
        double nm2 = fmax(fmin(m1, o1), fmax(m2, o2));
        m1 = nm1; m2 = nm2;
    }
    const double gs = m1 + m2;
    const int g = lane >> 3;

    int rank = 0;
#pragma unroll
    for (int j = 0; j < 8; ++j) {
        double gj = __shfl(gs, j * 8);
        rank += (gj > gs) || (gj == gs && j < g);
    }
    if (rank >= 4) { b0 = NINF; b1 = NINF; b2 = NINF; b3 = NINF; }

    int myidx = 0;
#pragma unroll
    for (int it = 0; it < 8; ++it) {
        double bv = b0; int bi = e0;
        if (b1 > bv) { bv = b1; bi = e0 + 1; }
        if (b2 > bv) { bv = b2; bi = e0 + 2; }
        if (b3 > bv) { bv = b3; bi = e0 + 3; }
#pragma unroll
        for (int w = 1; w < 64; w <<= 1) {
            double ov = __shfl_xor(bv, w);
            int    oi = __shfl_xor(bi, w);
            if (ov > bv || (ov == bv && oi < bi)) { bv = ov; bi = oi; }
        }
        if (lane == it) myidx = bi;
        if ((bi >> 2) == lane) {
            switch (bi & 3) {
                case 0: b0 = NINF; break;
                case 1: b1 = NINF; break;
                case 2: b2 = NINF; break;
                case 3: b3 = NINF; break;
            }
        }
    }

    double g0 = __shfl(s0, myidx >> 2);
    double g1 = __shfl(s1, myidx >> 2);
    double g2 = __shfl(s2, myidx >> 2);
    double g3 = __shfl(s3, myidx >> 2);
    const int ss = myidx & 3;
    double wval = (lane < 8) ? (ss == 0 ? g0 : ss == 1 ? g1 : ss == 2 ? g2 : g3) : 0.0;
    double s = wval;
    s += __shfl_xor(s, 1);
    s += __shfl_xor(s, 2);
    s += __shfl_xor(s, 4);
    if (lane < 8) {
        float wout = (float)(wval / (s + 1e-20) * 2.5);
        out[(size_t)token * 8 + lane] = wout;
        out[(size_t)MTOK * 8 + (size_t)token * 8 + lane] = (float)myidx;
    }
}

__global__ void init_k(int* count) { *count = 0; }

extern "C" void kernel_launch(void* const* d_in, const int* in_sizes, int n_in,
                              void* d_out, int out_size, void* d_ws, size_t ws_size,
                              hipStream_t stream) {
    const float* X    = (const float*)d_in[0];
    const float* W    = (const float*)d_in[1];
    const float* bias = (const float*)d_in[2];
    float* out = (float*)d_out;

    // ws: [0,16.8MB) Lf f32 scores, later aliased by Ldp f64 partials (rescore
    //     runs after route_flag, when Lf is dead). Then list, cnt, Wfrag.
    float*  Lf    = (float*)d_ws;
    double* Ldp   = (double*)d_ws;                        // 8*1024*256*8 = 16,777,216 B
    int*    list  = (int*)((char*)d_ws + 16777216);
    int*    cnt   = (int*)((char*)d_ws + 16777216 + CAPR * 4);
    f16*    Wfrag = (f16*)((char*)d_ws + 16777216 + 65536); // 7,340,032 B

    init_k<<<1, 1, 0, stream>>>(cnt);
    wconv_k<<<NEXP, 256, 0, stream>>>(W, Wfrag);

    gemm_v8_k<<<512, 512, 0, stream>>>(X, Wfrag, Lf);

    route_flag_k<<<MTOK / 4, 256, 0, stream>>>(Lf, bias, out, list, cnt);

    dim3 g3(CAPR / 64, NEXP / 64, KSPLIT);
    rescore_k<<<g3, 256, 0, stream>>>(X, W, list, cnt, Ldp);

    route_exact_k<<<CAPR, 64, 0, stream>>>(Ldp, bias, list, cnt, out);
}

// Round 9
// 469.453 us; speedup vs baseline: 15.6645x; 1.0908x over previous
//
#include <hip/hip_runtime.h>
#include <math.h>

#define MTOK 16384
#define NEXP 256
#define KDIM 7168

#define CAPR 1024
#define KSPLIT 8
#define KCH (KDIM / KSPLIT)   // 896
#define TAU 2e-5f

#define NKC 224               // K-chunks of 32
#define NSTEP 112             // BK=64 steps
// Wfrag layout: [hilo][nt 0..15][kc 0..223][lane 0..63][8 f16]
//   lane = k8*16 + col ; element j -> k = kc*32 + k8*8 + j, expert = nt*16 + col

typedef _Float16 f16;
typedef __attribute__((ext_vector_type(8))) f16 f16x8;
typedef __attribute__((ext_vector_type(4))) float f32x4;

__device__ __forceinline__ void cvt_hilo(const float4 a, const float4 b, f16x8* h, f16x8* l) {
    float xs[8] = {a.x, a.y, a.z, a.w, b.x, b.y, b.z, b.w};
#pragma unroll
    for (int e = 0; e < 8; ++e) {
        f16 hh = (f16)xs[e];
        (*h)[e] = hh;
        (*l)[e] = (f16)((xs[e] - (float)hh) * 2048.f);
    }
}

// ============ K0: W -> Wfrag (MFMA B-fragment order, hi/lo split) ============
__global__ void wconv_k(const float* __restrict__ W, f16* __restrict__ Wfrag) {
    const int e  = blockIdx.x;        // expert 0..255
    const int kc = threadIdx.x;       // 0..223 (256 threads, guard)
    if (kc >= NKC) return;
    const int nt  = e >> 4;
    const int col = e & 15;
    const float* src = W + (size_t)e * KDIM + kc * 32;
    float x[32];
#pragma unroll
    for (int i = 0; i < 8; ++i) {
        float4 v = *(const float4*)(src + i * 4);
        x[i * 4 + 0] = v.x; x[i * 4 + 1] = v.y; x[i * 4 + 2] = v.z; x[i * 4 + 3] = v.w;
    }
#pragma unroll
    for (int k8 = 0; k8 < 4; ++k8) {
        f16x8 h, l;
#pragma unroll
        for (int j = 0; j < 8; ++j) {
            float xv = x[k8 * 8 + j];
            f16 hh = (f16)xv;
            h[j] = hh;
            l[j] = (f16)((xv - (float)hh) * 2048.f);
        }
        const size_t lanepos = (size_t)(k8 * 16 + col) * 8;
        *(f16x8*)(Wfrag + (((size_t)(0 * 16 + nt) * NKC + kc) << 9) + lanepos) = h;
        *(f16x8*)(Wfrag + (((size_t)(1 * 16 + nt) * NKC + kc) << 9) + lanepos) = l;
    }
}

// ============ K1: fp16x2-split MFMA GEMM + sigmoid (v9) ============
// BM=128, BN=128; 8 waves (2M x 4N), wave tile 64x32; BK=64 per barrier.
// A via LDS dbuf (64 KB), distance-2 register prefetch; B direct from Wfrag
// with one-step register double-buffer. All register indexing static.
__launch_bounds__(512, 2)
__global__ void gemm_v9_k(const float* __restrict__ X,
                          const f16* __restrict__ Wfrag,
                          float* __restrict__ S) {
    __shared__ f16 A_lds[2][2][8][128][8];   // [buf][hilo][k8][row][8] = 64 KB

    const int tid  = threadIdx.x;
    const int lane = tid & 63;
    const int w    = tid >> 6;          // 0..7
    const int wr   = w >> 2;            // 0..1 (M half, 64 rows)
    const int wc   = w & 3;             // 0..3 (N quarter, 32 cols)

    // XCD-partitioned mapping: XCD 0-3 -> n-half 0, XCD 4-7 -> n-half 1
    const int id   = blockIdx.x;        // 0..255
    const int xcd  = id & 7;
    const int nb   = xcd >> 2;
    const int mb   = (id >> 3) * 4 + (xcd & 3);   // 0..127
    const int m0 = mb * 128;
    const int n0 = nb * 128;

    // A staging: thread stages row tid&127, k8-granules (tid>>7) and (tid>>7)+4
    const int arow = tid & 127;
    const int ag0  = tid >> 7;          // 0..3
    const float* xg = X + (size_t)(m0 + arow) * KDIM + ag0 * 8;

    const int fr = lane & 15;
    const int fq = lane >> 4;

    // B fragment bases: nt = nb*8 + wc*2 + {0,1}; lo at nt+16
    const int ntb = nb * 8 + wc * 2;
    const f16* wpH0 = Wfrag + (((size_t)(ntb + 0)  * NKC) << 9) + lane * 8;
    const f16* wpH1 = Wfrag + (((size_t)(ntb + 1)  * NKC) << 9) + lane * 8;
    const f16* wpL0 = Wfrag + (((size_t)(ntb + 16) * NKC) << 9) + lane * 8;
    const f16* wpL1 = Wfrag + (((size_t)(ntb + 17) * NKC) << 9) + lane * 8;

    f32x4 accA[4][2];
    f32x4 accB[4][2];
#pragma unroll
    for (int i = 0; i < 4; ++i)
#pragma unroll
        for (int j = 0; j < 2; ++j) { accA[i][j] = (f32x4)0.f; accB[i][j] = (f32x4)0.f; }

    // named prefetch registers (all statically indexed)
    float4 aE0, aE1, aE2, aE3, aO0, aO1, aO2, aO3;
    f16x8 p0, p1, p2, p3, p4, p5, p6, p7;   // B set P: [H0a,H1a,L0a,L1a,H0b,H1b,L0b,L1b]
    f16x8 q0, q1, q2, q3, q4, q5, q6, q7;   // B set Q

#define A_LOAD4(R0_, R1_, R2_, R3_, STEP_) do {                             \
        const int st_ = (STEP_) < NSTEP ? (STEP_) : (NSTEP - 1);            \
        const float* p_ = xg + (size_t)st_ * 64;                            \
        R0_ = *(const float4*)(p_ + 0);                                     \
        R1_ = *(const float4*)(p_ + 4);                                     \
        R2_ = *(const float4*)(p_ + 32);                                    \
        R3_ = *(const float4*)(p_ + 36);                                    \
    } while (0)

#define B_LOAD8(R0_,R1_,R2_,R3_,R4_,R5_,R6_,R7_, STEP_) do {                \
        const int st_ = (STEP_) < NSTEP ? (STEP_) : (NSTEP - 1);            \
        const size_t oa_ = ((size_t)(st_ * 2))     << 9;                    \
        const size_t ob_ = ((size_t)(st_ * 2 + 1)) << 9;                    \
        R0_ = *(const f16x8*)(wpH0 + oa_);                                  \
        R1_ = *(const f16x8*)(wpH1 + oa_);                                  \
        R2_ = *(const f16x8*)(wpL0 + oa_);                                  \
        R3_ = *(const f16x8*)(wpL1 + oa_);                                  \
        R4_ = *(const f16x8*)(wpH0 + ob_);                                  \
        R5_ = *(const f16x8*)(wpH1 + ob_);                                  \
        R6_ = *(const f16x8*)(wpL0 + ob_);                                  \
        R7_ = *(const f16x8*)(wpL1 + ob_);                                  \
    } while (0)

#define STORE_A4(BUF_, R0_, R1_, R2_, R3_) do {                             \
        f16x8 h_, l_;                                                       \
        cvt_hilo(R0_, R1_, &h_, &l_);                                       \
        *(f16x8*)&A_lds[BUF_][0][ag0][arow][0] = h_;                        \
        *(f16x8*)&A_lds[BUF_][1][ag0][arow][0] = l_;                        \
        cvt_hilo(R2_, R3_, &h_, &l_);                                       \
        *(f16x8*)&A_lds[BUF_][0][ag0 + 4][arow][0] = h_;                    \
        *(f16x8*)&A_lds[BUF_][1][ag0 + 4][arow][0] = l_;                    \
    } while (0)

#define MFMA16(A_, B_, C_) __builtin_amdgcn_mfma_f32_16x16x32_f16(A_, B_, C_, 0, 0, 0)

#define COMPUTE_CH(BUF_, K8O_, H0_, H1_, L0_, L1_) do {                     \
        f16x8 ah_[4], al_[4];                                               \
        _Pragma("unroll")                                                   \
        for (int mi_ = 0; mi_ < 4; ++mi_) {                                 \
            const int r_ = wr * 64 + mi_ * 16 + fr;                         \
            ah_[mi_] = *(const f16x8*)&A_lds[BUF_][0][(K8O_) + fq][r_][0];  \
            al_[mi_] = *(const f16x8*)&A_lds[BUF_][1][(K8O_) + fq][r_][0];  \
        }                                                                   \
        _Pragma("unroll")                                                   \
        for (int mi_ = 0; mi_ < 4; ++mi_) {                                 \
            accA[mi_][0] = MFMA16(ah_[mi_], H0_, accA[mi_][0]);             \
            accA[mi_][1] = MFMA16(ah_[mi_], H1_, accA[mi_][1]);             \
            accB[mi_][0] = MFMA16(ah_[mi_], L0_, accB[mi_][0]);             \
            accB[mi_][0] = MFMA16(al_[mi_], H0_, accB[mi_][0]);             \
            accB[mi_][1] = MFMA16(ah_[mi_], L1_, accB[mi_][1]);             \
            accB[mi_][1] = MFMA16(al_[mi_], H1_, accB[mi_][1]);             \
        }                                                                   \
    } while (0)

    // prologue: aE=A(0) -> buf0, aO=A(1), P=B(step 0)
    A_LOAD4(aE0, aE1, aE2, aE3, 0);
    A_LOAD4(aO0, aO1, aO2, aO3, 1);
    B_LOAD8(p0, p1, p2, p3, p4, p5, p6, p7, 0);
    STORE_A4(0, aE0, aE1, aE2, aE3);
    __syncthreads();

    for (int s = 0; s < NSTEP; s += 2) {
        // ---- even step s: buf0, B set P ----
        A_LOAD4(aE0, aE1, aE2, aE3, s + 2);
        B_LOAD8(q0, q1, q2, q3, q4, q5, q6, q7, s + 1);
        COMPUTE_CH(0, 0, p0, p1, p2, p3);
        COMPUTE_CH(0, 4, p4, p5, p6, p7);
        STORE_A4(1, aO0, aO1, aO2, aO3);   // A(s+1), loaded 1.5+ phases ago
        __syncthreads();

        // ---- odd step s+1: buf1, B set Q ----
        A_LOAD4(aO0, aO1, aO2, aO3, s + 3);
        B_LOAD8(p0, p1, p2, p3, p4, p5, p6, p7, s + 2);
        COMPUTE_CH(1, 0, q0, q1, q2, q3);
        COMPUTE_CH(1, 4, q4, q5, q6, q7);
        STORE_A4(0, aE0, aE1, aE2, aE3);   // A(s+2)
        __syncthreads();
    }

    // epilogue: combine, sigmoid, store (C layout: row=(lane>>4)*4+r, col=lane&15)
#pragma unroll
    for (int mi = 0; mi < 4; ++mi)
#pragma unroll
        for (int ni = 0; ni < 2; ++ni) {
            const int e = n0 + wc * 32 + ni * 16 + fr;
#pragma unroll
            for (int r = 0; r < 4; ++r) {
                const int m = m0 + wr * 64 + mi * 16 + fq * 4 + r;
                float logit = accA[mi][ni][r] + accB[mi][ni][r] * (1.f / 2048.f);
                S[(size_t)m * NEXP + e] = 1.f / (1.f + expf(-logit));
            }
        }
#undef A_LOAD4
#undef B_LOAD8
#undef STORE_A4
#undef MFMA16
#undef COMPUTE_CH
}

// ================= K2: f32 routing + margin flagging =================
__launch_bounds__(256)
__global__ void route_flag_k(const float* __restrict__ S,
                             const float* __restrict__ bias,
                             float* __restrict__ out,
                             int* __restrict__ list,
                             int* __restrict__ count) {
    __shared__ float sraw[4][256];
    const int wv   = threadIdx.x >> 6;
    const int lane = threadIdx.x & 63;
    const int token = blockIdx.x * 4 + wv;
    const float NINF = -__builtin_inff();
    const float PINF =  __builtin_inff();

    const float* row = S + (size_t)token * NEXP;
    float4 v = *(const float4*)(row + lane * 4);
    *(float4*)&sraw[wv][lane * 4] = v;

    const int e0 = lane * 4;
    float4 bi4 = *(const float4*)(bias + e0);
    float b0 = v.x + bi4.x;
    float b1 = v.y + bi4.y;
    float b2 = v.z + bi4.z;
    float b3 = v.w + bi4.w;

    bool flag = false;

    float m1 = b0, m2 = NINF;
    if (b1 > m1) { m2 = m1; m1 = b1; } else if (b1 > m2) m2 = b1;
    if (b2 > m1) { m2 = m1; m1 = b2; } else if (b2 > m2) m2 = b2;
    if (b3 > m1) { m2 = m1; m1 = b3; } else if (b3 > m2) m2 = b3;
#pragma unroll
    for (int w = 1; w <= 4; w <<= 1) {
        float o1 = __shfl_xor(m1, w);
        float o2 = __shfl_xor(m2, w);
        float nm1 = fmaxf(m1, o1);
        float nm2 = fmaxf(fminf(m1, o1), fmaxf(m2, o2));
        m1 = nm1; m2 = nm2;
    }
    const float gs = m1 + m2;
    const int g = lane >> 3;

    int rank = 0;
#pragma unroll
    for (int j = 0; j < 8; ++j) {
        float gj = __shfl(gs, j * 8);
        rank += (gj > gs) || (gj == gs && j < g);
    }
    const bool sel = rank < 4;

    {
        float a = sel ? gs : PINF;
        float b = sel ? NINF : gs;
#pragma unroll
        for (int w = 1; w < 64; w <<= 1) {
            a = fminf(a, __shfl_xor(a, w));
            b = fmaxf(b, __shfl_xor(b, w));
        }
        flag |= (a - b) < 2.f * TAU;
    }

    if (!sel) { b0 = NINF; b1 = NINF; b2 = NINF; b3 = NINF; }

    int myidx = 0;
    float prev = 0.f;
#pragma unroll
    for (int it = 0; it < 9; ++it) {
        float bv = b0; int bi = e0;
        if (b1 > bv) { bv = b1; bi = e0 + 1; }
        if (b2 > bv) { bv = b2; bi = e0 + 2; }
        if (b3 > bv) { bv = b3; bi = e0 + 3; }
#pragma unroll
        for (int w = 1; w < 64; w <<= 1) {
            float ov = __shfl_xor(bv, w);
            int   oi = __shfl_xor(bi, w);
            if (ov > bv || (ov == bv && oi < bi)) { bv = ov; bi = oi; }
        }
        if (it > 0) flag |= (prev - bv) < TAU;
        prev = bv;
        if (it < 8) {
            if (lane == it) myidx = bi;
            if ((bi >> 2) == lane) {
                switch (bi & 3) {
                    case 0: b0 = NINF; break;
                    case 1: b1 = NINF; break;
                    case 2: b2 = NINF; break;
                    case 3: b3 = NINF; break;
                }
            }
        }
    }

    const bool anyflag = __any((int)flag);

    __syncthreads();

    float wval = (lane < 8) ? sraw[wv][myidx] : 0.f;
    float s = wval;
    s += __shfl_xor(s, 1);
    s += __shfl_xor(s, 2);
    s += __shfl_xor(s, 4);
    if (lane < 8) {
        float wout = wval / (s + 1e-20f) * 2.5f;
        out[(size_t)token * 8 + lane] = wout;
        out[(size_t)MTOK * 8 + (size_t)token * 8 + lane] = (float)myidx;
    }

    if (anyflag && lane == 0) {
        int f = atomicAdd(count, 1);
        if (f < CAPR) list[f] = token;
    }
}

// ================= K3: K-split f64 partial GEMM over flagged rows =================
__launch_bounds__(256)
__global__ void rescore_k(const float* __restrict__ X,
                          const float* __restrict__ W,
                          const int* __restrict__ list,
                          const int* __restrict__ count,
                          double* __restrict__ Ldp) {
    const int cnt = min(*count, CAPR);
    const int m0 = blockIdx.x * 64;
    if (m0 >= cnt) return;
    const int n0 = blockIdx.y * 64;
    const int ks = blockIdx.z;
    const int kbase = ks * KCH;

    __shared__ float As[16][66];
    __shared__ float Bs[16][66];
    const int tid = threadIdx.x;
    const int row = tid >> 2;
    const int c   = tid & 3;
    const int tm  = tid >> 4;
    const int tn  = tid & 15;

    const int gi = list[min(m0 + row, cnt - 1)];
    const float* xg = X + (size_t)gi * KDIM + c * 4;
    const float* wg = W + (size_t)(n0 + row) * KDIM + c * 4;

    double acc[4][4];
#pragma unroll
    for (int i = 0; i < 4; ++i)
#pragma unroll
        for (int j = 0; j < 4; ++j) acc[i][j] = 0.0;

    for (int k0 = kbase; k0 < kbase + KCH; k0 += 16) {
        float4 a = *(const float4*)(xg + k0);
        float4 b = *(const float4*)(wg + k0);
        __syncthreads();
        As[c * 4 + 0][row] = a.x; As[c * 4 + 1][row] = a.y;
        As[c * 4 + 2][row] = a.z; As[c * 4 + 3][row] = a.w;
        Bs[c * 4 + 0][row] = b.x; Bs[c * 4 + 1][row] = b.y;
        Bs[c * 4 + 2][row] = b.z; Bs[c * 4 + 3][row] = b.w;
        __syncthreads();
#pragma unroll
        for (int k = 0; k < 16; ++k) {
            double ad[4], bd[4];
#pragma unroll
            for (int i = 0; i < 4; ++i) ad[i] = (double)As[k][tm * 4 + i];
#pragma unroll
            for (int j = 0; j < 4; ++j) bd[j] = (double)Bs[k][tn * 4 + j];
#pragma unroll
            for (int i = 0; i < 4; ++i)
#pragma unroll
                for (int j = 0; j < 4; ++j)
                    acc[i][j] = fma(ad[i], bd[j], acc[i][j]);
        }
    }

#pragma unroll
    for (int i = 0; i < 4; ++i) {
        const int r = m0 + tm * 4 + i;
        if (r < cnt) {
#pragma unroll
            for (int j = 0; j < 4; ++j)
                Ldp[((size_t)ks * CAPR + r) * NEXP + n0 + tn * 4 + j] = acc[i][j];
        }
    }
}

// ================= K4: exact f64 routing for flagged tokens =================
__launch_bounds__(64)
__global__ void route_exact_k(const double* __restrict__ Ldp,
                              const float* __restrict__ bias,
                              const int* __restrict__ list,
                              const int* __restrict__ count,
                              float* __restrict__ out) {
    const int cnt = min(*count, CAPR);
    const int f = blockIdx.x;
    if (f >= cnt) return;
    const int lane = threadIdx.x;
    const int token = list[f];
    const double NINF = -__builtin_inf();

    const int e0 = lane * 4;
    double l0 = 0.0, l1 = 0.0, l2 = 0.0, l3 = 0.0;
#pragma unroll
    for (int s = 0; s < KSPLIT; ++s) {
        double4 p = *(const double4*)(Ldp + ((size_t)s * CAPR + f) * NEXP + e0);
        l0 += p.x; l1 += p.y; l2 += p.z; l3 += p.w;
    }

    double s0 = 1.0 / (1.0 + exp(-l0));
    double s1 = 1.0 / (1.0 + exp(-l1));
    double s2 = 1.0 / (1.0 + exp(-l2));
    double s3 = 1.0 / (1.0 + exp(-l3));

    float4 bi4 = *(const float4*)(bias + e0);
    double b0 = s0 + (double)bi4.x;
    double b1 = s1 + (double)bi4.y;
    double b2 = s2 + (double)bi4.z;
    double b3 = s3 + (double)bi4.w;

    double m1 = b0, m2 = NINF;
    if (b1 > m1) { m2 = m1; m1 = b1; } else if (b1 > m2) m2 = b1;
    if (b2 > m1) { m2 = m1; m1 = b2; } else if (b2 > m2) m2 = b2;
    if (b3 > m1) { m2 = m1; m1 = b3; } else if (b3 > m2) m2 = b3;
#pragma unroll
    for (int w = 1; w <= 4; w <<= 1) {
        double o1 = __shfl_xor(m1, w);
        double o2 = __shfl_xor(m2, w);
        double nm1 = fmax(m1, o1);
        double nm2 = fmax(fmin(m1, o1), fmax(m2, o2));
        m1 = nm1; m2 = nm2;
    }
    const double gs = m1 + m2;
    const int g = lane >> 3;

    int rank = 0;
#pragma unroll
    for (int j = 0; j < 8; ++j) {
        double gj = __shfl(gs, j * 8);
        rank += (gj > gs) || (gj == gs && j < g);
    }
    if (rank >= 4) { b0 = NINF; b1 = NINF; b2 = NINF; b3 = NINF; }

    int myidx = 0;
#pragma unroll
    for (int it = 0; it < 8; ++it) {
        double bv = b0; int bi = e0;
        if (b1 > bv) { bv = b1; bi = e0 + 1; }
        if (b2 > bv) { bv = b2; bi = e0 + 2; }
        if (b3 > bv) { bv = b3; bi = e0 + 3; }
#pragma unroll
        for (int w = 1; w < 64; w <<= 1) {
            double ov = __shfl_xor(bv, w);
            int    oi = __shfl_xor(bi, w);
            if (ov > bv || (ov == bv && oi < bi)) { bv = ov; bi = oi; }
        }
        if (lane == it) myidx = bi;
        if ((bi >> 2) == lane) {
            switch (bi & 3) {
                case 0: b0 = NINF; break;
                case 1: b1 = NINF; break;
                case 2: b2 = NINF; break;
                case 3: b3 = NINF; break;
            }
        }
    }

    double g0 = __shfl(s0, myidx >> 2);
    double g1 = __shfl(s1, myidx >> 2);
    double g2 = __shfl(s2, myidx >> 2);
    double g3 = __shfl(s3, myidx >> 2);
    const int ss = myidx & 3;
    double wval = (lane < 8) ? (ss == 0 ? g0 : ss == 1 ? g1 : ss == 2 ? g2 : g3) : 0.0;
    double s = wval;
    s += __shfl_xor(s, 1);
    s += __shfl_xor(s, 2);
    s += __shfl_xor(s, 4);
    if (lane < 8) {
        float wout = (float)(wval / (s + 1e-20) * 2.5);
        out[(size_t)token * 8 + lane] = wout;
        out[(size_t)MTOK * 8 + (size_t)token * 8 + lane] = (float)myidx;
    }
}

__global__ void init_k(int* count) { *count = 0; }

extern "C" void kernel_launch(void* const* d_in, const int* in_sizes, int n_in,
                              void* d_out, int out_size, void* d_ws, size_t ws_size,
                              hipStream_t stream) {
    const float* X    = (const float*)d_in[0];
    const float* W    = (const float*)d_in[1];
    const float* bias = (const float*)d_in[2];
    float* out = (float*)d_out;

    // ws: [0,16.8MB) Lf f32 scores, later aliased by Ldp f64 partials (rescore
    //     runs after route_flag, when Lf is dead). Then list, cnt, Wfrag.
    float*  Lf    = (float*)d_ws;
    double* Ldp   = (double*)d_ws;                        // 8*1024*256*8 = 16,777,216 B
    int*    list  = (int*)((char*)d_ws + 16777216);
    int*    cnt   = (int*)((char*)d_ws + 16777216 + CAPR * 4);
    f16*    Wfrag = (f16*)((char*)d_ws + 16777216 + 65536); // 7,340,032 B

    init_k<<<1, 1, 0, stream>>>(cnt);
    wconv_k<<<NEXP, 256, 0, stream>>>(W, Wfrag);

    gemm_v9_k<<<256, 512, 0, stream>>>(X, Wfrag, Lf);

    route_flag_k<<<MTOK / 4, 256, 0, stream>>>(Lf, bias, out, list, cnt);

    dim3 g3(CAPR / 64, NEXP / 64, KSPLIT);
    rescore_k<<<g3, 256, 0, stream>>>(X, W, list, cnt, Ldp);

    route_exact_k<<<CAPR, 64, 0, stream>>>(Ldp, bias, list, cnt, out);
}

// Round 10
// 385.982 us; speedup vs baseline: 19.0520x; 1.2163x over previous
//
#include <hip/hip_runtime.h>
#include <math.h>

#define MTOK 16384
#define NEXP 256
#define KDIM 7168

#define CAPR 1024
#define KSPLIT 8
#define KCH (KDIM / KSPLIT)   // 896
#define TAU 2e-5f

#define NKC 224               // K-chunks of 32
#define NSTEP 112             // BK=64 steps
// Wfrag layout: [hilo][nt 0..15][kc 0..223][lane 0..63][8 f16]
//   lane = k8*16 + col ; element j -> k = kc*32 + k8*8 + j, expert = nt*16 + col

typedef _Float16 f16;
typedef __attribute__((ext_vector_type(8))) f16 f16x8;
typedef __attribute__((ext_vector_type(4))) f16 f16x4;
typedef __attribute__((ext_vector_type(4))) float f32x4;

__device__ __forceinline__ void cvt_hilo(const float4 a, const float4 b, f16x8* h, f16x8* l) {
    float xs[8] = {a.x, a.y, a.z, a.w, b.x, b.y, b.z, b.w};
#pragma unroll
    for (int e = 0; e < 8; ++e) {
        f16 hh = (f16)xs[e];
        (*h)[e] = hh;
        (*l)[e] = (f16)((xs[e] - (float)hh) * 2048.f);
    }
}

__device__ __forceinline__ void cvt_hilo4(const float4 a, f16x4* h, f16x4* l) {
    float xs[4] = {a.x, a.y, a.z, a.w};
#pragma unroll
    for (int e = 0; e < 4; ++e) {
        f16 hh = (f16)xs[e];
        (*h)[e] = hh;
        (*l)[e] = (f16)((xs[e] - (float)hh) * 2048.f);
    }
}

// ============ K0: W -> Wfrag (MFMA B-fragment order, hi/lo split) ============
__global__ void wconv_k(const float* __restrict__ W, f16* __restrict__ Wfrag) {
    const int e  = blockIdx.x;        // expert 0..255
    const int kc = threadIdx.x;       // 0..223 (256 threads, guard)
    if (kc >= NKC) return;
    const int nt  = e >> 4;
    const int col = e & 15;
    const float* src = W + (size_t)e * KDIM + kc * 32;
    float x[32];
#pragma unroll
    for (int i = 0; i < 8; ++i) {
        float4 v = *(const float4*)(src + i * 4);
        x[i * 4 + 0] = v.x; x[i * 4 + 1] = v.y; x[i * 4 + 2] = v.z; x[i * 4 + 3] = v.w;
    }
#pragma unroll
    for (int k8 = 0; k8 < 4; ++k8) {
        f16x8 h, l;
#pragma unroll
        for (int j = 0; j < 8; ++j) {
            float xv = x[k8 * 8 + j];
            f16 hh = (f16)xv;
            h[j] = hh;
            l[j] = (f16)((xv - (float)hh) * 2048.f);
        }
        const size_t lanepos = (size_t)(k8 * 16 + col) * 8;
        *(f16x8*)(Wfrag + (((size_t)(0 * 16 + nt) * NKC + kc) << 9) + lanepos) = h;
        *(f16x8*)(Wfrag + (((size_t)(1 * 16 + nt) * NKC + kc) << 9) + lanepos) = l;
    }
}

// ============ K1: fp16x2-split MFMA GEMM + sigmoid (v10) ============
// BM=128, BN=128; 8 waves (2M x 4N), wave tile 64x32; BK=64 per barrier.
// A via LDS dbuf (64 KB) with COALESCED global loads (16 full lines/instr),
// distance-2 register prefetch; B direct from Wfrag with one-step register
// double-buffer. All register indexing static.
__launch_bounds__(512, 2)
__global__ void gemm_v10_k(const float* __restrict__ X,
                           const f16* __restrict__ Wfrag,
                           float* __restrict__ S) {
    __shared__ f16 A_lds[2][2][8][128][8];   // [buf][hilo][k8][row][8] = 64 KB

    const int tid  = threadIdx.x;
    const int lane = tid & 63;
    const int w    = tid >> 6;          // 0..7
    const int wr   = w >> 2;            // 0..1 (M half, 64 rows)
    const int wc   = w & 3;             // 0..3 (N quarter, 32 cols)

    // XCD-partitioned mapping: XCD 0-3 -> n-half 0, XCD 4-7 -> n-half 1
    const int id   = blockIdx.x;        // 0..255
    const int xcd  = id & 7;
    const int nb   = xcd >> 2;
    const int mb   = (id >> 3) * 4 + (xcd & 3);   // 0..127
    const int m0 = mb * 128;
    const int n0 = nb * 128;

    // A staging (coalesced): thread t -> row t>>2, k-lane t&3.
    // Instruction i loads float4 at float-off kl*4 + i*16; per instr a wave
    // covers 16 rows x 64B contiguous (full cache lines).
    const int arow = tid >> 2;          // 0..127
    const int kl   = tid & 3;           // 0..3
    const float* xg = X + (size_t)(m0 + arow) * KDIM + kl * 4;
    const int ghalf = (kl & 1) * 4;     // f16 offset within granule
    const int gbase = kl >> 1;          // granule base: g = gbase + 2*i

    const int fr = lane & 15;
    const int fq = lane >> 4;

    // B fragment bases: nt = nb*8 + wc*2 + {0,1}; lo at nt+16
    const int ntb = nb * 8 + wc * 2;
    const f16* wpH0 = Wfrag + (((size_t)(ntb + 0)  * NKC) << 9) + lane * 8;
    const f16* wpH1 = Wfrag + (((size_t)(ntb + 1)  * NKC) << 9) + lane * 8;
    const f16* wpL0 = Wfrag + (((size_t)(ntb + 16) * NKC) << 9) + lane * 8;
    const f16* wpL1 = Wfrag + (((size_t)(ntb + 17) * NKC) << 9) + lane * 8;

    f32x4 accA[4][2];
    f32x4 accB[4][2];
#pragma unroll
    for (int i = 0; i < 4; ++i)
#pragma unroll
        for (int j = 0; j < 2; ++j) { accA[i][j] = (f32x4)0.f; accB[i][j] = (f32x4)0.f; }

    // named prefetch registers (all statically indexed)
    float4 aE0, aE1, aE2, aE3, aO0, aO1, aO2, aO3;
    f16x8 p0, p1, p2, p3, p4, p5, p6, p7;   // B set P
    f16x8 q0, q1, q2, q3, q4, q5, q6, q7;   // B set Q

#define A_LOAD4(R0_, R1_, R2_, R3_, STEP_) do {                             \
        const int st_ = (STEP_) < NSTEP ? (STEP_) : (NSTEP - 1);            \
        const float* p_ = xg + (size_t)st_ * 64;                            \
        R0_ = *(const float4*)(p_ + 0);                                     \
        R1_ = *(const float4*)(p_ + 16);                                    \
        R2_ = *(const float4*)(p_ + 32);                                    \
        R3_ = *(const float4*)(p_ + 48);                                    \
    } while (0)

#define B_LOAD8(R0_,R1_,R2_,R3_,R4_,R5_,R6_,R7_, STEP_) do {                \
        const int st_ = (STEP_) < NSTEP ? (STEP_) : (NSTEP - 1);            \
        const size_t oa_ = ((size_t)(st_ * 2))     << 9;                    \
        const size_t ob_ = ((size_t)(st_ * 2 + 1)) << 9;                    \
        R0_ = *(const f16x8*)(wpH0 + oa_);                                  \
        R1_ = *(const f16x8*)(wpH1 + oa_);                                  \
        R2_ = *(const f16x8*)(wpL0 + oa_);                                  \
        R3_ = *(const f16x8*)(wpL1 + oa_);                                  \
        R4_ = *(const f16x8*)(wpH0 + ob_);                                  \
        R5_ = *(const f16x8*)(wpH1 + ob_);                                  \
        R6_ = *(const f16x8*)(wpL0 + ob_);                                  \
        R7_ = *(const f16x8*)(wpL1 + ob_);                                  \
    } while (0)

    // store one float4 (half-granule) as hi/lo f16x4; g = gbase + 2*I_
#define ST_HG(BUF_, R_, I_) do {                                            \
        f16x4 h_, l_;                                                       \
        cvt_hilo4(R_, &h_, &l_);                                            \
        *(f16x4*)&A_lds[BUF_][0][gbase + 2 * (I_)][arow][ghalf] = h_;       \
        *(f16x4*)&A_lds[BUF_][1][gbase + 2 * (I_)][arow][ghalf] = l_;       \
    } while (0)

#define STORE_A4(BUF_, R0_, R1_, R2_, R3_) do {                             \
        ST_HG(BUF_, R0_, 0);                                                \
        ST_HG(BUF_, R1_, 1);                                                \
        ST_HG(BUF_, R2_, 2);                                                \
        ST_HG(BUF_, R3_, 3);                                                \
    } while (0)

#define MFMA16(A_, B_, C_) __builtin_amdgcn_mfma_f32_16x16x32_f16(A_, B_, C_, 0, 0, 0)

#define COMPUTE_CH(BUF_, K8O_, H0_, H1_, L0_, L1_) do {                     \
        f16x8 ah_[4], al_[4];                                               \
        _Pragma("unroll")                                                   \
        for (int mi_ = 0; mi_ < 4; ++mi_) {                                 \
            const int r_ = wr * 64 + mi_ * 16 + fr;                         \
            ah_[mi_] = *(const f16x8*)&A_lds[BUF_][0][(K8O_) + fq][r_][0];  \
            al_[mi_] = *(const f16x8*)&A_lds[BUF_][1][(K8O_) + fq][r_][0];  \
        }                                                                   \
        _Pragma("unroll")                                                   \
        for (int mi_ = 0; mi_ < 4; ++mi_) {                                 \
            accA[mi_][0] = MFMA16(ah_[mi_], H0_, accA[mi_][0]);             \
            accA[mi_][1] = MFMA16(ah_[mi_], H1_, accA[mi_][1]);             \
            accB[mi_][0] = MFMA16(ah_[mi_], L0_, accB[mi_][0]);             \
            accB[mi_][0] = MFMA16(al_[mi_], H0_, accB[mi_][0]);             \
            accB[mi_][1] = MFMA16(ah_[mi_], L1_, accB[mi_][1]);             \
            accB[mi_][1] = MFMA16(al_[mi_], H1_, accB[mi_][1]);             \
        }                                                                   \
    } while (0)

    // prologue: aE=A(0) -> buf0, aO=A(1), P=B(step 0)
    A_LOAD4(aE0, aE1, aE2, aE3, 0);
    A_LOAD4(aO0, aO1, aO2, aO3, 1);
    B_LOAD8(p0, p1, p2, p3, p4, p5, p6, p7, 0);
    STORE_A4(0, aE0, aE1, aE2, aE3);
    __syncthreads();

    for (int s = 0; s < NSTEP; s += 2) {
        // ---- even step s: buf0, B set P ----
        A_LOAD4(aE0, aE1, aE2, aE3, s + 2);
        B_LOAD8(q0, q1, q2, q3, q4, q5, q6, q7, s + 1);
        COMPUTE_CH(0, 0, p0, p1, p2, p3);
        COMPUTE_CH(0, 4, p4, p5, p6, p7);
        STORE_A4(1, aO0, aO1, aO2, aO3);   // A(s+1), loaded 1.5+ phases ago
        __syncthreads();

        // ---- odd step s+1: buf1, B set Q ----
        A_LOAD4(aO0, aO1, aO2, aO3, s + 3);
        B_LOAD8(p0, p1, p2, p3, p4, p5, p6, p7, s + 2);
        COMPUTE_CH(1, 0, q0, q1, q2, q3);
        COMPUTE_CH(1, 4, q4, q5, q6, q7);
        STORE_A4(0, aE0, aE1, aE2, aE3);   // A(s+2)
        __syncthreads();
    }

    // epilogue: combine, sigmoid, store (C layout: row=(lane>>4)*4+r, col=lane&15)
#pragma unroll
    for (int mi = 0; mi < 4; ++mi)
#pragma unroll
        for (int ni = 0; ni < 2; ++ni) {
            const int e = n0 + wc * 32 + ni * 16 + fr;
#pragma unroll
            for (int r = 0; r < 4; ++r) {
                const int m = m0 + wr * 64 + mi * 16 + fq * 4 + r;
                float logit = accA[mi][ni][r] + accB[mi][ni][r] * (1.f / 2048.f);
                S[(size_t)m * NEXP + e] = 1.f / (1.f + expf(-logit));
            }
        }
#undef A_LOAD4
#undef B_LOAD8
#undef ST_HG
#undef STORE_A4
#undef MFMA16
#undef COMPUTE_CH
}

// ================= K2: f32 routing + margin flagging =================
__launch_bounds__(256)
__global__ void route_flag_k(const float* __restrict__ S,
                             const float* __restrict__ bias,
                             float* __restrict__ out,
                             int* __restrict__ list,
                             int* __restrict__ count) {
    __shared__ float sraw[4][256];
    const int wv   = threadIdx.x >> 6;
    const int lane = threadIdx.x & 63;
    const int token = blockIdx.x * 4 + wv;
    const float NINF = -__builtin_inff();
    const float PINF =  __builtin_inff();

    const float* row = S + (size_t)token * NEXP;
    float4 v = *(const float4*)(row + lane * 4);
    *(float4*)&sraw[wv][lane * 4] = v;

    const int e0 = lane * 4;
    float4 bi4 = *(const float4*)(bias + e0);
    float b0 = v.x + bi4.x;
    float b1 = v.y + bi4.y;
    float b2 = v.z + bi4.z;
    float b3 = v.w + bi4.w;

    bool flag = false;

    float m1 = b0, m2 = NINF;
    if (b1 > m1) { m2 = m1; m1 = b1; } else if (b1 > m2) m2 = b1;
    if (b2 > m1) { m2 = m1; m1 = b2; } else if (b2 > m2) m2 = b2;
    if (b3 > m1) { m2 = m1; m1 = b3; } else if (b3 > m2) m2 = b3;
#pragma unroll
    for (int w = 1; w <= 4; w <<= 1) {
        float o1 = __shfl_xor(m1, w);
        float o2 = __shfl_xor(m2, w);
        float nm1 = fmaxf(m1, o1);
        float nm2 = fmaxf(fminf(m1, o1), fmaxf(m2, o2));
        m1 = nm1; m2 = nm2;
    }
    const float gs = m1 + m2;
    const int g = lane >> 3;

    int rank = 0;
#pragma unroll
    for (int j = 0; j < 8; ++j) {
        float gj = __shfl(gs, j * 8);
        rank += (gj > gs) || (gj == gs && j < g);
    }
    const bool sel = rank < 4;

    {
        float a = sel ? gs : PINF;
        float b = sel ? NINF : gs;
#pragma unroll
        for (int w = 1; w < 64; w <<= 1) {
            a = fminf(a, __shfl_xor(a, w));
            b = fmaxf(b, __shfl_xor(b, w));
        }
        flag |= (a - b) < 2.f * TAU;
    }

    if (!sel) { b0 = NINF; b1 = NINF; b2 = NINF; b3 = NINF; }

    int myidx = 0;
    float prev = 0.f;
#pragma unroll
    for (int it = 0; it < 9; ++it) {
        float bv = b0; int bi = e0;
        if (b1 > bv) { bv = b1; bi = e0 + 1; }
        if (b2 > bv) { bv = b2; bi = e0 + 2; }
        if (b3 > bv) { bv = b3; bi = e0 + 3; }
#pragma unroll
        for (int w = 1; w < 64; w <<= 1) {
            float ov = __shfl_xor(bv, w);
            int   oi = __shfl_xor(bi, w);
            if (ov > bv || (ov == bv && oi < bi)) { bv = ov; bi = oi; }
        }
        if (it > 0) flag |= (prev - bv) < TAU;
        prev = bv;
        if (it < 8) {
            if (lane == it) myidx = bi;
            if ((bi >> 2) == lane) {
                switch (bi & 3) {
                    case 0: b0 = NINF; break;
                    case 1: b1 = NINF; break;
                    case 2: b2 = NINF; break;
                    case 3: b3 = NINF; break;
                }
            }
        }
    }

    const bool anyflag = __any((int)flag);

    __syncthreads();

    float wval = (lane < 8) ? sraw[wv][myidx] : 0.f;
    float s = wval;
    s += __shfl_xor(s, 1);
    s += __shfl_xor(s, 2);
    s += __shfl_xor(s, 4);
    if (lane < 8) {
        float wout = wval / (s + 1e-20f) * 2.5f;
        out[(size_t)token * 8 + lane] = wout;
        out[(size_t)MTOK * 8 + (size_t)token * 8 + lane] = (float)myidx;
    }

    if (anyflag && lane == 0) {
        int f = atomicAdd(count, 1);
        if (f < CAPR) list[f] = token;
    }
}

// ================= K3: K-split f64 partial GEMM over flagged rows =================
__launch_bounds__(256)
__global__ void rescore_k(const float* __restrict__ X,
                          const float* __restrict__ W,
                          const int* __restrict__ list,
                          const int* __restrict__ count,
                          double* __restrict__ Ldp) {
    const int cnt = min(*count, CAPR);
    const int m0 = blockIdx.x * 64;
    if (m0 >= cnt) return;
    const int n0 = blockIdx.y * 64;
    const int ks = blockIdx.z;
    const int kbase = ks * KCH;

    __shared__ float As[16][66];
    __shared__ float Bs[16][66];
    const int tid = threadIdx.x;
    const int row = tid >> 2;
    const int c   = tid & 3;
    const int tm  = tid >> 4;
    const int tn  = tid & 15;

    const int gi = list[min(m0 + row, cnt - 1)];
    const float* xg = X + (size_t)gi * KDIM + c * 4;
    const float* wg = W + (size_t)(n0 + row) * KDIM + c * 4;

    double acc[4][4];
#pragma unroll
    for (int i = 0; i < 4; ++i)
#pragma unroll
        for (int j = 0; j < 4; ++j) acc[i][j] = 0.0;

    for (int k0 = kbase; k0 < kbase + KCH; k0 += 16) {
        float4 a = *(const float4*)(xg + k0);
        float4 b = *(const float4*)(wg + k0);
        __syncthreads();
        As[c * 4 + 0][row] = a.x; As[c * 4 + 1][row] = a.y;
        As[c * 4 + 2][row] = a.z; As[c * 4 + 3][row] = a.w;
        Bs[c * 4 + 0][row] = b.x; Bs[c * 4 + 1][row] = b.y;
        Bs[c * 4 + 2][row] = b.z; Bs[c * 4 + 3][row] = b.w;
        __syncthreads();
#pragma unroll
        for (int k = 0; k < 16; ++k) {
            double ad[4], bd[4];
#pragma unroll
            for (int i = 0; i < 4; ++i) ad[i] = (double)As[k][tm * 4 + i];
#pragma unroll
            for (int j = 0; j < 4; ++j) bd[j] = (double)Bs[k][tn * 4 + j];
#pragma unroll
            for (int i = 0; i < 4; ++i)
#pragma unroll
                for (int j = 0; j < 4; ++j)
                    acc[i][j] = fma(ad[i], bd[j], acc[i][j]);
        }
    }

#pragma unroll
    for (int i = 0; i < 4; ++i) {
        const int r = m0 + tm * 4 + i;
        if (r < cnt) {
#pragma unroll
            for (int j = 0; j < 4; ++j)
                Ldp[((size_t)ks * CAPR + r) * NEXP + n0 + tn * 4 + j] = acc[i][j];
        }
    }
}

// ================= K4: exact f64 routing for flagged tokens =================
__launch_bounds__(64)
__global__ void route_exact_k(const double* __restrict__ Ldp,
                              const float* __restrict__ bias,
                              const int* __restrict__ list,
                              const int* __restrict__ count,
                              float* __restrict__ out) {
    const int cnt = min(*count, CAPR);
    const int f = blockIdx.x;
    if (f >= cnt) return;
    const int lane = threadIdx.x;
    const int token = list[f];
    const double NINF = -__builtin_inf();

    const int e0 = lane * 4;
    double l0 = 0.0, l1 = 0.0, l2 = 0.0, l3 = 0.0;
#pragma unroll
    for (int s = 0; s < KSPLIT; ++s) {
        double4 p = *(const double4*)(Ldp + ((size_t)s * CAPR + f) * NEXP + e0);
        l0 += p.x; l1 += p.y; l2 += p.z; l3 += p.w;
    }

    double s0 = 1.0 / (1.0 + exp(-l0));
    double s1 = 1.0 / (1.0 + exp(-l1));
    double s2 = 1.0 / (1.0 + exp(-l2));
    double s3 = 1.0 / (1.0 + exp(-l3));

    float4 bi4 = *(const float4*)(bias + e0);
    double b0 = s0 + (double)bi4.x;
    double b1 = s1 + (double)bi4.y;
    double b2 = s2 + (double)bi4.z;
    double b3 = s3 + (double)bi4.w;

    double m1 = b0, m2 = NINF;
    if (b1 > m1) { m2 = m1; m1 = b1; } else if (b1 > m2) m2 = b1;
    if (b2 > m1) { m2 = m1; m1 = b2; } else if (b2 > m2) m2 = b2;
    if (b3 > m1) { m2 = m1; m1 = b3; } else if (b3 > m2) m2 = b3;
#pragma unroll
    for (int w = 1; w <= 4; w <<= 1) {
        double o1 = __shfl_xor(m1, w);
        double o2 = __shfl_xor(m2, w);
        double nm1 = fmax(m1, o1);
        double nm2 = fmax(fmin(m1, o1), fmax(m2, o2));
        m1 = nm1; m2 = nm2;
    }
    const double gs = m1 + m2;
    const int g = lane >> 3;

    int rank = 0;
#pragma unroll
    for (int j = 0; j < 8; ++j) {
        double gj = __shfl(gs, j * 8);
        rank += (gj > gs) || (gj == gs && j < g);
    }
    if (rank >= 4) { b0 = NINF; b1 = NINF; b2 = NINF; b3 = NINF; }

    int myidx = 0;
#pragma unroll
    for (int it = 0; it < 8; ++it) {
        double bv = b0; int bi = e0;
        if (b1 > bv) { bv = b1; bi = e0 + 1; }
        if (b2 > bv) { bv = b2; bi = e0 + 2; }
        if (b3 > bv) { bv = b3; bi = e0 + 3; }
#pragma unroll
        for (int w = 1; w < 64; w <<= 1) {
            double ov = __shfl_xor(bv, w);
            int    oi = __shfl_xor(bi, w);
            if (ov > bv || (ov == bv && oi < bi)) { bv = ov; bi = oi; }
        }
        if (lane == it) myidx = bi;
        if ((bi >> 2) == lane) {
            switch (bi & 3) {
                case 0: b0 = NINF; break;
                case 1: b1 = NINF; break;
                case 2: b2 = NINF; break;
                case 3: b3 = NINF; break;
            }
        }
    }

    double g0 = __shfl(s0, myidx >> 2);
    double g1 = __shfl(s1, myidx >> 2);
    double g2 = __shfl(s2, myidx >> 2);
    double g3 = __shfl(s3, myidx >> 2);
    const int ss = myidx & 3;
    double wval = (lane < 8) ? (ss == 0 ? g0 : ss == 1 ? g1 : ss == 2 ? g2 : g3) : 0.0;
    double s = wval;
    s += __shfl_xor(s, 1);
    s += __shfl_xor(s, 2);
    s += __shfl_xor(s, 4);
    if (lane < 8) {
        float wout = (float)(wval / (s + 1e-20) * 2.5);
        out[(size_t)token * 8 + lane] = wout;
        out[(size_t)MTOK * 8 + (size_t)token * 8 + lane] = (float)myidx;
    }
}

__global__ void init_k(int* count) { *count = 0; }

extern "C" void kernel_launch(void* const* d_in, const int* in_sizes, int n_in,
                              void* d_out, int out_size, void* d_ws, size_t ws_size,
                              hipStream_t stream) {
    const float* X    = (const float*)d_in[0];
    const float* W    = (const float*)d_in[1];
    const float* bias = (const float*)d_in[2];
    float* out = (float*)d_out;

    // ws: [0,16.8MB) Lf f32 scores, later aliased by Ldp f64 partials (rescore
    //     runs after route_flag, when Lf is dead). Then list, cnt, Wfrag.
    float*  Lf    = (float*)d_ws;
    double* Ldp   = (double*)d_ws;                        // 8*1024*256*8 = 16,777,216 B
    int*    list  = (int*)((char*)d_ws + 16777216);
    int*    cnt   = (int*)((char*)d_ws + 16777216 + CAPR * 4);
    f16*    Wfrag = (f16*)((char*)d_ws + 16777216 + 65536); // 7,340,032 B

    init_k<<<1, 1, 0, stream>>>(cnt);
    wconv_k<<<NEXP, 256, 0, stream>>>(W, Wfrag);

    gemm_v10_k<<<256, 512, 0, stream>>>(X, Wfrag, Lf);

    route_flag_k<<<MTOK / 4, 256, 0, stream>>>(Lf, bias, out, list, cnt);

    dim3 g3(CAPR / 64, NEXP / 64, KSPLIT);
    rescore_k<<<g3, 256, 0, stream>>>(X, W, list, cnt, Ldp);

    route_exact_k<<<CAPR, 64, 0, stream>>>(Ldp, bias, list, cnt, out);
}